// Round 4
// baseline (367.219 us; speedup 1.0000x reference)
//
#include <hip/hip_runtime.h>
#include <hip/hip_bf16.h>

typedef __attribute__((ext_vector_type(4))) float f32x4;
typedef __attribute__((ext_vector_type(8))) short bf16x8;

#define AS1 __attribute__((address_space(1)))
#define AS3 __attribute__((address_space(3)))

__device__ __forceinline__ void gload16(const void* g, void* l) {
    __builtin_amdgcn_global_load_lds((AS1 const void*)g, (AS3 void*)l, 16, 0, 0);
}

__device__ __forceinline__ unsigned short f2bf(float f) {
    union { float f; unsigned int u; } v; v.f = f;
    unsigned int u = v.u;
    unsigned int r = (u + 0x7FFFu + ((u >> 16) & 1u)) >> 16;
    return (unsigned short)r;
}

__device__ __forceinline__ float gelu_t(float x) {
    float u = 0.7978845608028654f * (x + 0.044715f * x * x * x);
    return 0.5f * x * (1.0f + tanhf(u));
}

// ---------------------------------------------------------------------------
// Generic bf16 GEMM: C(MxN) = A(MxK) @ Bt(NxK)^T  [+ epilogue]
// EPI 0: store bf16 | EPI 1: v+bias[col]+res -> f32 | EPI 2: gelu(v+bias)->bf16
// 128x128 tile, BK=32, 256 threads (4 waves, 2x2), m97 2-barrier structure.
// ---------------------------------------------------------------------------
template<int EPI>
__global__ __launch_bounds__(256) void gemm_bt(
    const unsigned short* __restrict__ A,
    const unsigned short* __restrict__ Bt,
    void* __restrict__ C,
    const float* __restrict__ bias,
    const float* __restrict__ res,
    int M, int N, int K)
{
    __shared__ alignas(16) unsigned short As[128 * 32];
    __shared__ alignas(16) unsigned short Bs[128 * 32];
    const int t = threadIdx.x;
    const int lane = t & 63;
    const int w = t >> 6;
    const int la = lane & 15, lg = lane >> 4;
    const int brow = blockIdx.x * 128, bcol = blockIdx.y * 128;
    const int wr = (w >> 1) * 64, wc = (w & 1) * 64;

    const int srow = t >> 2;
    const int scol = (t & 3) * 8;
    const unsigned short* aS0 = A + (size_t)(brow + srow) * K + scol;
    const unsigned short* aS1 = A + (size_t)(brow + 64 + srow) * K + scol;
    const unsigned short* bS0 = Bt + (size_t)(bcol + srow) * K + scol;
    const unsigned short* bS1 = Bt + (size_t)(bcol + 64 + srow) * K + scol;
    unsigned short* aD = As + t * 8;
    unsigned short* bD = Bs + t * 8;

    f32x4 acc[4][4];
#pragma unroll
    for (int m = 0; m < 4; m++)
#pragma unroll
        for (int n = 0; n < 4; n++)
            acc[m][n] = (f32x4){0.f, 0.f, 0.f, 0.f};

    for (int k0 = 0; k0 < K; k0 += 32) {
        __syncthreads();
        gload16(aS0 + k0, aD);
        gload16(aS1 + k0, aD + 2048);
        gload16(bS0 + k0, bD);
        gload16(bS1 + k0, bD + 2048);
        __syncthreads();

        bf16x8 af[4], bfv[4];
#pragma unroll
        for (int m = 0; m < 4; m++)
            af[m] = *(const bf16x8*)(As + (wr + m * 16 + la) * 32 + lg * 8);
#pragma unroll
        for (int n = 0; n < 4; n++)
            bfv[n] = *(const bf16x8*)(Bs + (wc + n * 16 + la) * 32 + lg * 8);
#pragma unroll
        for (int m = 0; m < 4; m++)
#pragma unroll
            for (int n = 0; n < 4; n++)
                acc[m][n] = __builtin_amdgcn_mfma_f32_16x16x32_bf16(
                    af[m], bfv[n], acc[m][n], 0, 0, 0);
    }

#pragma unroll
    for (int m = 0; m < 4; m++)
#pragma unroll
        for (int n = 0; n < 4; n++)
#pragma unroll
            for (int j = 0; j < 4; j++) {
                int row = brow + wr + m * 16 + lg * 4 + j;
                int col = bcol + wc + n * 16 + la;
                float v = acc[m][n][j];
                if (EPI == 0) {
                    ((unsigned short*)C)[(size_t)row * N + col] = f2bf(v);
                } else if (EPI == 1) {
                    ((float*)C)[(size_t)row * N + col] =
                        v + bias[col] + res[(size_t)row * N + col];
                } else {
                    ((unsigned short*)C)[(size_t)row * N + col] =
                        f2bf(gelu_t(v + bias[col]));
                }
            }
}

// ---------------------------------------------------------------------------
// Split-K grouped GEMM for small grids (N=1024 -> only 256 blocks at 128x128).
// ---------------------------------------------------------------------------
template<int EPI>
__global__ __launch_bounds__(1024) void gemm_bt_ks(
    const unsigned short* __restrict__ A,
    const unsigned short* __restrict__ Bt,
    void* __restrict__ C,
    const float* __restrict__ bias,
    const float* __restrict__ res,
    int M, int N, int K)
{
    __shared__ alignas(16) char smem[128 * 132 * 4];
    const int t = threadIdx.x;
    const int g = t >> 8;
    const int tl = t & 255;
    const int lane = t & 63;
    const int w = tl >> 6;
    const int la = lane & 15, lg = lane >> 4;
    const int brow = blockIdx.x * 128, bcol = blockIdx.y * 128;
    const int wr = (w >> 1) * 64, wc = (w & 1) * 64;

    const int Kg = K >> 2;
    const int kbase = g * Kg;
    unsigned short* Asg = (unsigned short*)(smem + g * 16384);
    unsigned short* Bsg = Asg + 4096;

    const int srow = tl >> 2;
    const int scol = (tl & 3) * 8;
    const unsigned short* aS0 = A + (size_t)(brow + srow) * K + kbase + scol;
    const unsigned short* aS1 = A + (size_t)(brow + 64 + srow) * K + kbase + scol;
    const unsigned short* bS0 = Bt + (size_t)(bcol + srow) * K + kbase + scol;
    const unsigned short* bS1 = Bt + (size_t)(bcol + 64 + srow) * K + kbase + scol;
    unsigned short* aD = Asg + tl * 8;
    unsigned short* bD = Bsg + tl * 8;

    f32x4 acc[4][4];
#pragma unroll
    for (int m = 0; m < 4; m++)
#pragma unroll
        for (int n = 0; n < 4; n++)
            acc[m][n] = (f32x4){0.f, 0.f, 0.f, 0.f};

    for (int k0 = 0; k0 < Kg; k0 += 32) {
        __syncthreads();
        gload16(aS0 + k0, aD);
        gload16(aS1 + k0, aD + 2048);
        gload16(bS0 + k0, bD);
        gload16(bS1 + k0, bD + 2048);
        __syncthreads();

        bf16x8 af[4], bfv[4];
#pragma unroll
        for (int m = 0; m < 4; m++)
            af[m] = *(const bf16x8*)(Asg + (wr + m * 16 + la) * 32 + lg * 8);
#pragma unroll
        for (int n = 0; n < 4; n++)
            bfv[n] = *(const bf16x8*)(Bsg + (wc + n * 16 + la) * 32 + lg * 8);
#pragma unroll
        for (int m = 0; m < 4; m++)
#pragma unroll
            for (int n = 0; n < 4; n++)
                acc[m][n] = __builtin_amdgcn_mfma_f32_16x16x32_bf16(
                    af[m], bfv[n], acc[m][n], 0, 0, 0);
    }

    float* cbuf = (float*)smem;
    for (int s = 3; s >= 1; --s) {
        __syncthreads();
        if (g == s) {
#pragma unroll
            for (int m = 0; m < 4; m++)
#pragma unroll
                for (int n = 0; n < 4; n++)
#pragma unroll
                    for (int j = 0; j < 4; j++)
                        cbuf[(wr + m * 16 + lg * 4 + j) * 132 + wc + n * 16 + la] =
                            acc[m][n][j];
        }
        __syncthreads();
        if (g == 0) {
#pragma unroll
            for (int m = 0; m < 4; m++)
#pragma unroll
                for (int n = 0; n < 4; n++)
#pragma unroll
                    for (int j = 0; j < 4; j++)
                        acc[m][n][j] +=
                            cbuf[(wr + m * 16 + lg * 4 + j) * 132 + wc + n * 16 + la];
        }
    }
    if (g != 0) return;

#pragma unroll
    for (int m = 0; m < 4; m++)
#pragma unroll
        for (int n = 0; n < 4; n++)
#pragma unroll
            for (int j = 0; j < 4; j++) {
                int row = brow + wr + m * 16 + lg * 4 + j;
                int col = bcol + wc + n * 16 + la;
                float v = acc[m][n][j];
                if (EPI == 0) {
                    ((unsigned short*)C)[(size_t)row * N + col] = f2bf(v);
                } else if (EPI == 1) {
                    ((float*)C)[(size_t)row * N + col] =
                        v + bias[col] + res[(size_t)row * N + col];
                } else {
                    ((unsigned short*)C)[(size_t)row * N + col] =
                        f2bf(gelu_t(v + bias[col]));
                }
            }
}

// ---------------------------------------------------------------------------
// Causal flash attention. Grid (32,16,2) = 1024 blocks (4/CU), longest-first:
// qt = 31 - blockIdx.x so 32-tile blocks dispatch before 1-tile blocks.
// Scale folded into exp2 constant: p = exp2((s_raw - m_raw) * 0.125*log2(e)).
// ---------------------------------------------------------------------------
__global__ __launch_bounds__(256) void attn_kernel(
    const unsigned short* __restrict__ QKV,
    const unsigned short* __restrict__ Vt,
    unsigned short* __restrict__ ctx)
{
    __shared__ alignas(16) unsigned short Ks[64 * 64];
    __shared__ alignas(16) unsigned short Vs[64 * 64];
    __shared__ alignas(16) unsigned short Ps[4][16 * 64];
    const int t = threadIdx.x, lane = t & 63, w = t >> 6;
    const int la = lane & 15, lg = lane >> 4;
    const int qt = 31 - blockIdx.x, h = blockIdx.y, b = blockIdx.z;
    const int qbase = qt * 64;
    const float C2 = 0.18033688011112042f;  // 0.125 * log2(e)

    const unsigned short* kg = QKV + (size_t)(b * 2048) * 3072 + 1024 + h * 64;
    const unsigned short* vg = Vt + (size_t)((b * 16 + h) * 64) * 2048;
    const int srow = t >> 3;
    const int sxcol = (((t & 7) ^ (srow & 7)) * 8);

    unsigned short* pw = (unsigned short*)Ps[w];
    const int xk = la & 7;

    const unsigned short* qp =
        QKV + (size_t)(b * 2048 + qbase + w * 16 + la) * 3072 + h * 64;
    bf16x8 qf0 = *(const bf16x8*)(qp + lg * 8);
    bf16x8 qf1 = *(const bf16x8*)(qp + 32 + lg * 8);

    f32x4 o[4];
#pragma unroll
    for (int n = 0; n < 4; n++) o[n] = (f32x4){0.f, 0.f, 0.f, 0.f};
    float mrow[4] = {-1e30f, -1e30f, -1e30f, -1e30f};
    float lrow[4] = {0.f, 0.f, 0.f, 0.f};

    const int nt = qt + 1;
    for (int kt = 0; kt < nt; ++kt) {
        const int kv = kt * 64;
        __syncthreads();
        gload16(kg + (size_t)(kv + srow) * 3072 + sxcol, Ks + t * 8);
        gload16(kg + (size_t)(kv + 32 + srow) * 3072 + sxcol, Ks + 2048 + t * 8);
        gload16(vg + (size_t)srow * 2048 + kv + sxcol, Vs + t * 8);
        gload16(vg + (size_t)(32 + srow) * 2048 + kv + sxcol, Vs + 2048 + t * 8);
        __syncthreads();

        f32x4 sa[4];
        __builtin_amdgcn_s_setprio(1);
#pragma unroll
        for (int n = 0; n < 4; n++) {
            f32x4 z = (f32x4){0.f, 0.f, 0.f, 0.f};
            const unsigned short* kr = Ks + (n * 16 + la) * 64;
            bf16x8 k0 = *(const bf16x8*)(kr + (lg ^ xk) * 8);
            bf16x8 k1 = *(const bf16x8*)(kr + ((4 | lg) ^ xk) * 8);
            z = __builtin_amdgcn_mfma_f32_16x16x32_bf16(qf0, k0, z, 0, 0, 0);
            z = __builtin_amdgcn_mfma_f32_16x16x32_bf16(qf1, k1, z, 0, 0, 0);
            sa[n] = z;
        }
        __builtin_amdgcn_s_setprio(0);
        const bool diag = (kt == nt - 1);
        if (diag) {
#pragma unroll
            for (int n = 0; n < 4; n++)
#pragma unroll
                for (int j = 0; j < 4; j++) {
                    int qr = qbase + w * 16 + lg * 4 + j;
                    int kc = kv + n * 16 + la;
                    if (kc > qr) sa[n][j] = -1e30f;
                }
        }
        float pm[4];
#pragma unroll
        for (int j = 0; j < 4; j++)
            pm[j] = fmaxf(fmaxf(sa[0][j], sa[1][j]), fmaxf(sa[2][j], sa[3][j]));
#pragma unroll
        for (int off = 1; off < 16; off <<= 1)
#pragma unroll
            for (int j = 0; j < 4; j++)
                pm[j] = fmaxf(pm[j], __shfl_xor(pm[j], off, 64));
        float alpha[4];
#pragma unroll
        for (int j = 0; j < 4; j++) {
            float mn = fmaxf(mrow[j], pm[j]);
            alpha[j] = exp2f((mrow[j] - mn) * C2);
            mrow[j] = mn;
        }
        float psum[4] = {0.f, 0.f, 0.f, 0.f};
#pragma unroll
        for (int n = 0; n < 4; n++)
#pragma unroll
            for (int j = 0; j < 4; j++) {
                float pr = exp2f((sa[n][j] - mrow[j]) * C2);
                sa[n][j] = pr;
                psum[j] += pr;
            }
#pragma unroll
        for (int off = 1; off < 16; off <<= 1)
#pragma unroll
            for (int j = 0; j < 4; j++)
                psum[j] += __shfl_xor(psum[j], off, 64);
#pragma unroll
        for (int j = 0; j < 4; j++) {
            lrow[j] = lrow[j] * alpha[j] + psum[j];
            o[0][j] *= alpha[j]; o[1][j] *= alpha[j];
            o[2][j] *= alpha[j]; o[3][j] *= alpha[j];
        }
#pragma unroll
        for (int n = 0; n < 4; n++)
#pragma unroll
            for (int j = 0; j < 4; j++) {
                int qr = lg * 4 + j;
                int col = n * 16 + la;
                pw[qr * 64 + (((col >> 3) ^ (qr & 7)) * 8) + (col & 7)] =
                    f2bf(sa[n][j]);
            }
        asm volatile("s_waitcnt lgkmcnt(0)" ::: "memory");
        __builtin_amdgcn_s_setprio(1);
#pragma unroll
        for (int kk = 0; kk < 2; kk++) {
            bf16x8 pa = *(const bf16x8*)(pw + la * 64 + (((kk * 4 + lg) ^ xk) * 8));
#pragma unroll
            for (int n = 0; n < 4; n++) {
                bf16x8 vb = *(const bf16x8*)(
                    Vs + (n * 16 + la) * 64 + (((kk * 4 + lg) ^ xk) * 8));
                o[n] = __builtin_amdgcn_mfma_f32_16x16x32_bf16(pa, vb, o[n], 0, 0, 0);
            }
        }
        __builtin_amdgcn_s_setprio(0);
    }
    float inv[4];
#pragma unroll
    for (int j = 0; j < 4; j++) inv[j] = 1.0f / lrow[j];
#pragma unroll
    for (int n = 0; n < 4; n++)
#pragma unroll
        for (int j = 0; j < 4; j++) {
            int row = b * 2048 + qbase + w * 16 + lg * 4 + j;
            int col = h * 64 + n * 16 + la;
            ctx[(size_t)row * 1024 + col] = f2bf(o[n][j] * inv[j]);
        }
}

// ---------------------------------------------------------------------------
__global__ __launch_bounds__(256) void ln_kernel(
    const float* __restrict__ x, const float* __restrict__ scale,
    const float* __restrict__ shift, unsigned short* __restrict__ out)
{
    const int row = blockIdx.x, t = threadIdx.x;
    const int lane = t & 63, w = t >> 6;
    const float4 v = ((const float4*)(x + (size_t)row * 1024))[t];
    float s = v.x + v.y + v.z + v.w;
#pragma unroll
    for (int off = 1; off < 64; off <<= 1) s += __shfl_xor(s, off, 64);
    __shared__ float red[8];
    if (lane == 0) red[w] = s;
    __syncthreads();
    float mean = (red[0] + red[1] + red[2] + red[3]) * (1.0f / 1024.0f);
    float d0 = v.x - mean, d1 = v.y - mean, d2 = v.z - mean, d3 = v.w - mean;
    float q = d0 * d0 + d1 * d1 + d2 * d2 + d3 * d3;
#pragma unroll
    for (int off = 1; off < 64; off <<= 1) q += __shfl_xor(q, off, 64);
    if (lane == 0) red[4 + w] = q;
    __syncthreads();
    float var = (red[4] + red[5] + red[6] + red[7]) * (1.0f / 1023.0f);
    float rinv = rsqrtf(var + 1e-6f);
    const int c = t * 4;
    out[(size_t)row * 1024 + c + 0] = f2bf(scale[c + 0] * (d0 * rinv) + shift[c + 0]);
    out[(size_t)row * 1024 + c + 1] = f2bf(scale[c + 1] * (d1 * rinv) + shift[c + 1]);
    out[(size_t)row * 1024 + c + 2] = f2bf(scale[c + 2] * (d2 * rinv) + shift[c + 2]);
    out[(size_t)row * 1024 + c + 3] = f2bf(scale[c + 3] * (d3 * rinv) + shift[c + 3]);
}

// ---------------------------------------------------------------------------
__global__ __launch_bounds__(256) void transpose_w(
    const float* __restrict__ W, unsigned short* __restrict__ Wt, int K, int N)
{
    __shared__ float tile[32][33];
    const int nb = blockIdx.x * 32, kb = blockIdx.y * 32;
    const int tx = threadIdx.x, ty = threadIdx.y;
#pragma unroll
    for (int j = 0; j < 4; j++)
        tile[ty + j * 8][tx] = W[(size_t)(kb + ty + j * 8) * N + nb + tx];
    __syncthreads();
#pragma unroll
    for (int j = 0; j < 4; j++)
        Wt[(size_t)(nb + ty + j * 8) * K + kb + tx] = f2bf(tile[tx][ty + j * 8]);
}

// ---------------------------------------------------------------------------
__global__ __launch_bounds__(256) void transpose_v(
    const unsigned short* __restrict__ QKV, unsigned short* __restrict__ Vt)
{
    __shared__ unsigned short tile[32][33];
    const int sb = blockIdx.x * 32, hb = blockIdx.y * 32;
    const int bh = blockIdx.z;
    const int b = bh >> 4, h = bh & 15;
    const int tx = threadIdx.x, ty = threadIdx.y;
    const unsigned short* src = QKV + (size_t)(b * 2048) * 3072 + 2048 + h * 64;
#pragma unroll
    for (int j = 0; j < 4; j++)
        tile[ty + j * 8][tx] = src[(size_t)(sb + ty + j * 8) * 3072 + hb + tx];
    __syncthreads();
    unsigned short* dst = Vt + (size_t)((b * 16 + h) * 64) * 2048;
#pragma unroll
    for (int j = 0; j < 4; j++)
        dst[(size_t)(hb + ty + j * 8) * 2048 + sb + tx] = tile[tx][ty + j * 8];
}

// ---------------------------------------------------------------------------
extern "C" void kernel_launch(void* const* d_in, const int* in_sizes, int n_in,
                              void* d_out, int out_size, void* d_ws, size_t ws_size,
                              hipStream_t stream)
{
    const float* x      = (const float*)d_in[0];
    const float* Wq     = (const float*)d_in[1];
    const float* Wk     = (const float*)d_in[2];
    const float* Wv     = (const float*)d_in[3];
    const float* Wo     = (const float*)d_in[4];
    const float* bo     = (const float*)d_in[5];
    const float* W1     = (const float*)d_in[6];
    const float* b1     = (const float*)d_in[7];
    const float* W2     = (const float*)d_in[8];
    const float* b2     = (const float*)d_in[9];
    const float* scale1 = (const float*)d_in[10];
    const float* shift1 = (const float*)d_in[11];
    const float* scale2 = (const float*)d_in[12];
    const float* shift2 = (const float*)d_in[13];
    float* out = (float*)d_out;

    char* ws = (char*)d_ws;
    unsigned short* xn    = (unsigned short*)(ws);                   // 8MB (also yn)
    unsigned short* QKV   = (unsigned short*)(ws + (8ull << 20));    // 24MB
    unsigned short* VtB   = (unsigned short*)(ws + (32ull << 20));   // 8MB
    unsigned short* ctx   = (unsigned short*)(ws + (40ull << 20));   // 8MB
    unsigned short* g     = (unsigned short*)(ws + (8ull << 20));    // 32MB (reuse QKV+Vt)
    unsigned short* WqkvT = (unsigned short*)(ws + (48ull << 20));   // 6MB
    unsigned short* WoT   = (unsigned short*)(ws + (54ull << 20));   // 2MB
    unsigned short* W1T   = (unsigned short*)(ws + (56ull << 20));   // 8MB
    unsigned short* W2T   = (unsigned short*)(ws + (64ull << 20));   // 8MB -> 72MB total
    float* h = out;  // h lives in d_out

    dim3 blk(256);
    dim3 tb(32, 8);

    transpose_w<<<dim3(32, 32), tb, 0, stream>>>(Wq, WqkvT, 1024, 1024);
    transpose_w<<<dim3(32, 32), tb, 0, stream>>>(Wk, WqkvT + 1024 * 1024, 1024, 1024);
    transpose_w<<<dim3(32, 32), tb, 0, stream>>>(Wv, WqkvT + 2 * 1024 * 1024, 1024, 1024);
    transpose_w<<<dim3(32, 32), tb, 0, stream>>>(Wo, WoT, 1024, 1024);
    transpose_w<<<dim3(128, 32), tb, 0, stream>>>(W1, W1T, 1024, 4096);
    transpose_w<<<dim3(32, 128), tb, 0, stream>>>(W2, W2T, 4096, 1024);

    ln_kernel<<<4096, blk, 0, stream>>>(x, scale1, shift1, xn);
    gemm_bt<0><<<dim3(32, 24), blk, 0, stream>>>(xn, WqkvT, QKV, nullptr, nullptr,
                                                 4096, 3072, 1024);
    transpose_v<<<dim3(64, 2, 32), tb, 0, stream>>>(QKV, VtB);
    // unpaired, longest-first: 1024 blocks = 4/CU
    attn_kernel<<<dim3(32, 16, 2), blk, 0, stream>>>(QKV, VtB, ctx);
    gemm_bt_ks<1><<<dim3(32, 8), dim3(1024), 0, stream>>>(ctx, WoT, h, bo, x,
                                                          4096, 1024, 1024);
    ln_kernel<<<4096, blk, 0, stream>>>(h, scale2, shift2, xn);
    gemm_bt<2><<<dim3(32, 32), blk, 0, stream>>>(xn, W1T, g, b1, nullptr, 4096, 4096, 1024);
    gemm_bt_ks<1><<<dim3(32, 8), dim3(1024), 0, stream>>>(g, W2T, out, b2, h,
                                                          4096, 1024, 4096);
}

// Round 5
// 313.932 us; speedup vs baseline: 1.1697x; 1.1697x over previous
//
#include <hip/hip_runtime.h>
#include <hip/hip_bf16.h>

typedef __attribute__((ext_vector_type(4))) float f32x4;
typedef __attribute__((ext_vector_type(8))) short bf16x8;

#define AS1 __attribute__((address_space(1)))
#define AS3 __attribute__((address_space(3)))

__device__ __forceinline__ void gload16(const void* g, void* l) {
    __builtin_amdgcn_global_load_lds((AS1 const void*)g, (AS3 void*)l, 16, 0, 0);
}

__device__ __forceinline__ unsigned short f2bf(float f) {
    union { float f; unsigned int u; } v; v.f = f;
    unsigned int u = v.u;
    unsigned int r = (u + 0x7FFFu + ((u >> 16) & 1u)) >> 16;
    return (unsigned short)r;
}

__device__ __forceinline__ float gelu_t(float x) {
    float u = 0.7978845608028654f * (x + 0.044715f * x * x * x);
    return 0.5f * x * (1.0f + tanhf(u));
}

// ---------------------------------------------------------------------------
// Generic bf16 GEMM: C(MxN) = A(MxK) @ Bt(NxK)^T  [+ epilogue]
// EPI 0: store bf16 | EPI 1: v+bias[col]+res -> f32 | EPI 2: gelu(v+bias)->bf16
// 128x128 tile, BK=32, 256 threads (4 waves, 2x2), m97 2-barrier structure.
// ---------------------------------------------------------------------------
template<int EPI>
__global__ __launch_bounds__(256) void gemm_bt(
    const unsigned short* __restrict__ A,
    const unsigned short* __restrict__ Bt,
    void* __restrict__ C,
    const float* __restrict__ bias,
    const float* __restrict__ res,
    int M, int N, int K)
{
    __shared__ alignas(16) unsigned short As[128 * 32];
    __shared__ alignas(16) unsigned short Bs[128 * 32];
    const int t = threadIdx.x;
    const int lane = t & 63;
    const int w = t >> 6;
    const int la = lane & 15, lg = lane >> 4;
    const int brow = blockIdx.x * 128, bcol = blockIdx.y * 128;
    const int wr = (w >> 1) * 64, wc = (w & 1) * 64;

    const int srow = t >> 2;
    const int scol = (t & 3) * 8;
    const unsigned short* aS0 = A + (size_t)(brow + srow) * K + scol;
    const unsigned short* aS1 = A + (size_t)(brow + 64 + srow) * K + scol;
    const unsigned short* bS0 = Bt + (size_t)(bcol + srow) * K + scol;
    const unsigned short* bS1 = Bt + (size_t)(bcol + 64 + srow) * K + scol;
    unsigned short* aD = As + t * 8;
    unsigned short* bD = Bs + t * 8;

    f32x4 acc[4][4];
#pragma unroll
    for (int m = 0; m < 4; m++)
#pragma unroll
        for (int n = 0; n < 4; n++)
            acc[m][n] = (f32x4){0.f, 0.f, 0.f, 0.f};

    for (int k0 = 0; k0 < K; k0 += 32) {
        __syncthreads();
        gload16(aS0 + k0, aD);
        gload16(aS1 + k0, aD + 2048);
        gload16(bS0 + k0, bD);
        gload16(bS1 + k0, bD + 2048);
        __syncthreads();

        bf16x8 af[4], bfv[4];
#pragma unroll
        for (int m = 0; m < 4; m++)
            af[m] = *(const bf16x8*)(As + (wr + m * 16 + la) * 32 + lg * 8);
#pragma unroll
        for (int n = 0; n < 4; n++)
            bfv[n] = *(const bf16x8*)(Bs + (wc + n * 16 + la) * 32 + lg * 8);
#pragma unroll
        for (int m = 0; m < 4; m++)
#pragma unroll
            for (int n = 0; n < 4; n++)
                acc[m][n] = __builtin_amdgcn_mfma_f32_16x16x32_bf16(
                    af[m], bfv[n], acc[m][n], 0, 0, 0);
    }

#pragma unroll
    for (int m = 0; m < 4; m++)
#pragma unroll
        for (int n = 0; n < 4; n++)
#pragma unroll
            for (int j = 0; j < 4; j++) {
                int row = brow + wr + m * 16 + lg * 4 + j;
                int col = bcol + wc + n * 16 + la;
                float v = acc[m][n][j];
                if (EPI == 0) {
                    ((unsigned short*)C)[(size_t)row * N + col] = f2bf(v);
                } else if (EPI == 1) {
                    ((float*)C)[(size_t)row * N + col] =
                        v + bias[col] + res[(size_t)row * N + col];
                } else {
                    ((unsigned short*)C)[(size_t)row * N + col] =
                        f2bf(gelu_t(v + bias[col]));
                }
            }
}

// ---------------------------------------------------------------------------
// Split-K grouped GEMM for small grids (N=1024 -> only 256 blocks at 128x128).
// ---------------------------------------------------------------------------
template<int EPI>
__global__ __launch_bounds__(1024) void gemm_bt_ks(
    const unsigned short* __restrict__ A,
    const unsigned short* __restrict__ Bt,
    void* __restrict__ C,
    const float* __restrict__ bias,
    const float* __restrict__ res,
    int M, int N, int K)
{
    __shared__ alignas(16) char smem[128 * 132 * 4];
    const int t = threadIdx.x;
    const int g = t >> 8;
    const int tl = t & 255;
    const int lane = t & 63;
    const int w = tl >> 6;
    const int la = lane & 15, lg = lane >> 4;
    const int brow = blockIdx.x * 128, bcol = blockIdx.y * 128;
    const int wr = (w >> 1) * 64, wc = (w & 1) * 64;

    const int Kg = K >> 2;
    const int kbase = g * Kg;
    unsigned short* Asg = (unsigned short*)(smem + g * 16384);
    unsigned short* Bsg = Asg + 4096;

    const int srow = tl >> 2;
    const int scol = (tl & 3) * 8;
    const unsigned short* aS0 = A + (size_t)(brow + srow) * K + kbase + scol;
    const unsigned short* aS1 = A + (size_t)(brow + 64 + srow) * K + kbase + scol;
    const unsigned short* bS0 = Bt + (size_t)(bcol + srow) * K + kbase + scol;
    const unsigned short* bS1 = Bt + (size_t)(bcol + 64 + srow) * K + kbase + scol;
    unsigned short* aD = Asg + tl * 8;
    unsigned short* bD = Bsg + tl * 8;

    f32x4 acc[4][4];
#pragma unroll
    for (int m = 0; m < 4; m++)
#pragma unroll
        for (int n = 0; n < 4; n++)
            acc[m][n] = (f32x4){0.f, 0.f, 0.f, 0.f};

    for (int k0 = 0; k0 < Kg; k0 += 32) {
        __syncthreads();
        gload16(aS0 + k0, aD);
        gload16(aS1 + k0, aD + 2048);
        gload16(bS0 + k0, bD);
        gload16(bS1 + k0, bD + 2048);
        __syncthreads();

        bf16x8 af[4], bfv[4];
#pragma unroll
        for (int m = 0; m < 4; m++)
            af[m] = *(const bf16x8*)(Asg + (wr + m * 16 + la) * 32 + lg * 8);
#pragma unroll
        for (int n = 0; n < 4; n++)
            bfv[n] = *(const bf16x8*)(Bsg + (wc + n * 16 + la) * 32 + lg * 8);
#pragma unroll
        for (int m = 0; m < 4; m++)
#pragma unroll
            for (int n = 0; n < 4; n++)
                acc[m][n] = __builtin_amdgcn_mfma_f32_16x16x32_bf16(
                    af[m], bfv[n], acc[m][n], 0, 0, 0);
    }

    float* cbuf = (float*)smem;
    for (int s = 3; s >= 1; --s) {
        __syncthreads();
        if (g == s) {
#pragma unroll
            for (int m = 0; m < 4; m++)
#pragma unroll
                for (int n = 0; n < 4; n++)
#pragma unroll
                    for (int j = 0; j < 4; j++)
                        cbuf[(wr + m * 16 + lg * 4 + j) * 132 + wc + n * 16 + la] =
                            acc[m][n][j];
        }
        __syncthreads();
        if (g == 0) {
#pragma unroll
            for (int m = 0; m < 4; m++)
#pragma unroll
                for (int n = 0; n < 4; n++)
#pragma unroll
                    for (int j = 0; j < 4; j++)
                        acc[m][n][j] +=
                            cbuf[(wr + m * 16 + lg * 4 + j) * 132 + wc + n * 16 + la];
        }
    }
    if (g != 0) return;

#pragma unroll
    for (int m = 0; m < 4; m++)
#pragma unroll
        for (int n = 0; n < 4; n++)
#pragma unroll
            for (int j = 0; j < 4; j++) {
                int row = brow + wr + m * 16 + lg * 4 + j;
                int col = bcol + wc + n * 16 + la;
                float v = acc[m][n][j];
                if (EPI == 0) {
                    ((unsigned short*)C)[(size_t)row * N + col] = f2bf(v);
                } else if (EPI == 1) {
                    ((float*)C)[(size_t)row * N + col] =
                        v + bias[col] + res[(size_t)row * N + col];
                } else {
                    ((unsigned short*)C)[(size_t)row * N + col] =
                        f2bf(gelu_t(v + bias[col]));
                }
            }
}

// ---------------------------------------------------------------------------
// Causal flash attention: paired q-tiles (p, 31-p) for balance (33 iters/blk),
// double-buffered KV staging (prefetch kt+1 under compute of kt).
// Per-CU aliasing note: qt must NOT be a pure function of blockIdx.x % 32
// in an unpaired grid (round-4 regression: co-resident blocks share x).
// ---------------------------------------------------------------------------
__global__ __launch_bounds__(256) void attn_kernel(
    const unsigned short* __restrict__ QKV,
    const unsigned short* __restrict__ Vt,
    unsigned short* __restrict__ ctx)
{
    __shared__ alignas(16) unsigned short Ks[2][64 * 64];
    __shared__ alignas(16) unsigned short Vs[2][64 * 64];
    __shared__ alignas(16) unsigned short Ps[4][16 * 64];
    const int t = threadIdx.x, lane = t & 63, w = t >> 6;
    const int la = lane & 15, lg = lane >> 4;
    const int p = blockIdx.x, h = blockIdx.y, b = blockIdx.z;
    const float C2 = 0.18033688011112042f;  // 0.125 * log2(e)

    const unsigned short* kg = QKV + (size_t)(b * 2048) * 3072 + 1024 + h * 64;
    const unsigned short* vg = Vt + (size_t)((b * 16 + h) * 64) * 2048;
    const int srow = t >> 3;
    const int sxcol = (((t & 7) ^ (srow & 7)) * 8);

    unsigned short* pw = (unsigned short*)Ps[w];
    const int xk = la & 7;

    for (int half = 0; half < 2; ++half) {
        const int qt = half ? (31 - p) : p;
        const int qbase = qt * 64;

        const unsigned short* qp =
            QKV + (size_t)(b * 2048 + qbase + w * 16 + la) * 3072 + h * 64;
        bf16x8 qf0 = *(const bf16x8*)(qp + lg * 8);
        bf16x8 qf1 = *(const bf16x8*)(qp + 32 + lg * 8);

        f32x4 o[4];
#pragma unroll
        for (int n = 0; n < 4; n++) o[n] = (f32x4){0.f, 0.f, 0.f, 0.f};
        float mrow[4] = {-1e30f, -1e30f, -1e30f, -1e30f};
        float lrow[4] = {0.f, 0.f, 0.f, 0.f};

        const int nt = qt + 1;
        // all waves done reading LDS from previous half before restaging buf0
        __syncthreads();
        // prologue: stage tile 0 into buffer 0
        gload16(kg + (size_t)srow * 3072 + sxcol, Ks[0] + t * 8);
        gload16(kg + (size_t)(32 + srow) * 3072 + sxcol, Ks[0] + 2048 + t * 8);
        gload16(vg + (size_t)srow * 2048 + sxcol, Vs[0] + t * 8);
        gload16(vg + (size_t)(32 + srow) * 2048 + sxcol, Vs[0] + 2048 + t * 8);

        int cur = 0;
        for (int kt = 0; kt < nt; ++kt) {
            const int kv = kt * 64;
            __syncthreads();   // drains vmcnt: buf[cur] staged; prev reads done
            if (kt + 1 < nt) {
                const int kv2 = kv + 64;
                unsigned short* kd = Ks[cur ^ 1];
                unsigned short* vd = Vs[cur ^ 1];
                gload16(kg + (size_t)(kv2 + srow) * 3072 + sxcol, kd + t * 8);
                gload16(kg + (size_t)(kv2 + 32 + srow) * 3072 + sxcol, kd + 2048 + t * 8);
                gload16(vg + (size_t)srow * 2048 + kv2 + sxcol, vd + t * 8);
                gload16(vg + (size_t)(32 + srow) * 2048 + kv2 + sxcol, vd + 2048 + t * 8);
            }
            const unsigned short* Kc = Ks[cur];
            const unsigned short* Vc = Vs[cur];

            f32x4 sa[4];
            __builtin_amdgcn_s_setprio(1);
#pragma unroll
            for (int n = 0; n < 4; n++) {
                f32x4 z = (f32x4){0.f, 0.f, 0.f, 0.f};
                const unsigned short* kr = Kc + (n * 16 + la) * 64;
                bf16x8 k0 = *(const bf16x8*)(kr + (lg ^ xk) * 8);
                bf16x8 k1 = *(const bf16x8*)(kr + ((4 | lg) ^ xk) * 8);
                z = __builtin_amdgcn_mfma_f32_16x16x32_bf16(qf0, k0, z, 0, 0, 0);
                z = __builtin_amdgcn_mfma_f32_16x16x32_bf16(qf1, k1, z, 0, 0, 0);
                sa[n] = z;
            }
            __builtin_amdgcn_s_setprio(0);
            if (kt == nt - 1) {
#pragma unroll
                for (int n = 0; n < 4; n++)
#pragma unroll
                    for (int j = 0; j < 4; j++) {
                        int qr = qbase + w * 16 + lg * 4 + j;
                        int kc = kv + n * 16 + la;
                        if (kc > qr) sa[n][j] = -1e30f;
                    }
            }
            float pm[4];
#pragma unroll
            for (int j = 0; j < 4; j++)
                pm[j] = fmaxf(fmaxf(sa[0][j], sa[1][j]), fmaxf(sa[2][j], sa[3][j]));
#pragma unroll
            for (int off = 1; off < 16; off <<= 1)
#pragma unroll
                for (int j = 0; j < 4; j++)
                    pm[j] = fmaxf(pm[j], __shfl_xor(pm[j], off, 64));
            float alpha[4];
#pragma unroll
            for (int j = 0; j < 4; j++) {
                float mn = fmaxf(mrow[j], pm[j]);
                alpha[j] = exp2f((mrow[j] - mn) * C2);
                mrow[j] = mn;
            }
            float psum[4] = {0.f, 0.f, 0.f, 0.f};
#pragma unroll
            for (int n = 0; n < 4; n++)
#pragma unroll
                for (int j = 0; j < 4; j++) {
                    float pr = exp2f((sa[n][j] - mrow[j]) * C2);
                    sa[n][j] = pr;
                    psum[j] += pr;
                }
#pragma unroll
            for (int off = 1; off < 16; off <<= 1)
#pragma unroll
                for (int j = 0; j < 4; j++)
                    psum[j] += __shfl_xor(psum[j], off, 64);
#pragma unroll
            for (int j = 0; j < 4; j++) {
                lrow[j] = lrow[j] * alpha[j] + psum[j];
                o[0][j] *= alpha[j]; o[1][j] *= alpha[j];
                o[2][j] *= alpha[j]; o[3][j] *= alpha[j];
            }
#pragma unroll
            for (int n = 0; n < 4; n++)
#pragma unroll
                for (int j = 0; j < 4; j++) {
                    int qr = lg * 4 + j;
                    int col = n * 16 + la;
                    pw[qr * 64 + (((col >> 3) ^ (qr & 7)) * 8) + (col & 7)] =
                        f2bf(sa[n][j]);
                }
            asm volatile("s_waitcnt lgkmcnt(0)" ::: "memory");
            __builtin_amdgcn_s_setprio(1);
#pragma unroll
            for (int kk = 0; kk < 2; kk++) {
                bf16x8 pa = *(const bf16x8*)(pw + la * 64 + (((kk * 4 + lg) ^ xk) * 8));
#pragma unroll
                for (int n = 0; n < 4; n++) {
                    bf16x8 vb = *(const bf16x8*)(
                        Vc + (n * 16 + la) * 64 + (((kk * 4 + lg) ^ xk) * 8));
                    o[n] = __builtin_amdgcn_mfma_f32_16x16x32_bf16(pa, vb, o[n], 0, 0, 0);
                }
            }
            __builtin_amdgcn_s_setprio(0);
            cur ^= 1;
        }
        float inv[4];
#pragma unroll
        for (int j = 0; j < 4; j++) inv[j] = 1.0f / lrow[j];
#pragma unroll
        for (int n = 0; n < 4; n++)
#pragma unroll
            for (int j = 0; j < 4; j++) {
                int row = b * 2048 + qbase + w * 16 + lg * 4 + j;
                int col = h * 64 + n * 16 + la;
                ctx[(size_t)row * 1024 + col] = f2bf(o[n][j] * inv[j]);
            }
    }
}

// ---------------------------------------------------------------------------
__global__ __launch_bounds__(256) void ln_kernel(
    const float* __restrict__ x, const float* __restrict__ scale,
    const float* __restrict__ shift, unsigned short* __restrict__ out)
{
    const int row = blockIdx.x, t = threadIdx.x;
    const int lane = t & 63, w = t >> 6;
    const float4 v = ((const float4*)(x + (size_t)row * 1024))[t];
    float s = v.x + v.y + v.z + v.w;
#pragma unroll
    for (int off = 1; off < 64; off <<= 1) s += __shfl_xor(s, off, 64);
    __shared__ float red[8];
    if (lane == 0) red[w] = s;
    __syncthreads();
    float mean = (red[0] + red[1] + red[2] + red[3]) * (1.0f / 1024.0f);
    float d0 = v.x - mean, d1 = v.y - mean, d2 = v.z - mean, d3 = v.w - mean;
    float q = d0 * d0 + d1 * d1 + d2 * d2 + d3 * d3;
#pragma unroll
    for (int off = 1; off < 64; off <<= 1) q += __shfl_xor(q, off, 64);
    if (lane == 0) red[4 + w] = q;
    __syncthreads();
    float var = (red[4] + red[5] + red[6] + red[7]) * (1.0f / 1023.0f);
    float rinv = rsqrtf(var + 1e-6f);
    const int c = t * 4;
    out[(size_t)row * 1024 + c + 0] = f2bf(scale[c + 0] * (d0 * rinv) + shift[c + 0]);
    out[(size_t)row * 1024 + c + 1] = f2bf(scale[c + 1] * (d1 * rinv) + shift[c + 1]);
    out[(size_t)row * 1024 + c + 2] = f2bf(scale[c + 2] * (d2 * rinv) + shift[c + 2]);
    out[(size_t)row * 1024 + c + 3] = f2bf(scale[c + 3] * (d3 * rinv) + shift[c + 3]);
}

// ---------------------------------------------------------------------------
__global__ __launch_bounds__(256) void transpose_w(
    const float* __restrict__ W, unsigned short* __restrict__ Wt, int K, int N)
{
    __shared__ float tile[32][33];
    const int nb = blockIdx.x * 32, kb = blockIdx.y * 32;
    const int tx = threadIdx.x, ty = threadIdx.y;
#pragma unroll
    for (int j = 0; j < 4; j++)
        tile[ty + j * 8][tx] = W[(size_t)(kb + ty + j * 8) * N + nb + tx];
    __syncthreads();
#pragma unroll
    for (int j = 0; j < 4; j++)
        Wt[(size_t)(nb + ty + j * 8) * K + kb + tx] = f2bf(tile[tx][ty + j * 8]);
}

// ---------------------------------------------------------------------------
__global__ __launch_bounds__(256) void transpose_v(
    const unsigned short* __restrict__ QKV, unsigned short* __restrict__ Vt)
{
    __shared__ unsigned short tile[32][33];
    const int sb = blockIdx.x * 32, hb = blockIdx.y * 32;
    const int bh = blockIdx.z;
    const int b = bh >> 4, h = bh & 15;
    const int tx = threadIdx.x, ty = threadIdx.y;
    const unsigned short* src = QKV + (size_t)(b * 2048) * 3072 + 2048 + h * 64;
#pragma unroll
    for (int j = 0; j < 4; j++)
        tile[ty + j * 8][tx] = src[(size_t)(sb + ty + j * 8) * 3072 + hb + tx];
    __syncthreads();
    unsigned short* dst = Vt + (size_t)((b * 16 + h) * 64) * 2048;
#pragma unroll
    for (int j = 0; j < 4; j++)
        dst[(size_t)(hb + ty + j * 8) * 2048 + sb + tx] = tile[tx][ty + j * 8];
}

// ---------------------------------------------------------------------------
extern "C" void kernel_launch(void* const* d_in, const int* in_sizes, int n_in,
                              void* d_out, int out_size, void* d_ws, size_t ws_size,
                              hipStream_t stream)
{
    const float* x      = (const float*)d_in[0];
    const float* Wq     = (const float*)d_in[1];
    const float* Wk     = (const float*)d_in[2];
    const float* Wv     = (const float*)d_in[3];
    const float* Wo     = (const float*)d_in[4];
    const float* bo     = (const float*)d_in[5];
    const float* W1     = (const float*)d_in[6];
    const float* b1     = (const float*)d_in[7];
    const float* W2     = (const float*)d_in[8];
    const float* b2     = (const float*)d_in[9];
    const float* scale1 = (const float*)d_in[10];
    const float* shift1 = (const float*)d_in[11];
    const float* scale2 = (const float*)d_in[12];
    const float* shift2 = (const float*)d_in[13];
    float* out = (float*)d_out;

    char* ws = (char*)d_ws;
    unsigned short* xn    = (unsigned short*)(ws);                   // 8MB (also yn)
    unsigned short* QKV   = (unsigned short*)(ws + (8ull << 20));    // 24MB
    unsigned short* VtB   = (unsigned short*)(ws + (32ull << 20));   // 8MB
    unsigned short* ctx   = (unsigned short*)(ws + (40ull << 20));   // 8MB
    unsigned short* g     = (unsigned short*)(ws + (8ull << 20));    // 32MB (reuse QKV+Vt)
    unsigned short* WqkvT = (unsigned short*)(ws + (48ull << 20));   // 6MB
    unsigned short* WoT   = (unsigned short*)(ws + (54ull << 20));   // 2MB
    unsigned short* W1T   = (unsigned short*)(ws + (56ull << 20));   // 8MB
    unsigned short* W2T   = (unsigned short*)(ws + (64ull << 20));   // 8MB -> 72MB total
    float* h = out;  // h lives in d_out

    dim3 blk(256);
    dim3 tb(32, 8);

    transpose_w<<<dim3(32, 32), tb, 0, stream>>>(Wq, WqkvT, 1024, 1024);
    transpose_w<<<dim3(32, 32), tb, 0, stream>>>(Wk, WqkvT + 1024 * 1024, 1024, 1024);
    transpose_w<<<dim3(32, 32), tb, 0, stream>>>(Wv, WqkvT + 2 * 1024 * 1024, 1024, 1024);
    transpose_w<<<dim3(32, 32), tb, 0, stream>>>(Wo, WoT, 1024, 1024);
    transpose_w<<<dim3(128, 32), tb, 0, stream>>>(W1, W1T, 1024, 4096);
    transpose_w<<<dim3(32, 128), tb, 0, stream>>>(W2, W2T, 4096, 1024);

    ln_kernel<<<4096, blk, 0, stream>>>(x, scale1, shift1, xn);
    gemm_bt<0><<<dim3(32, 24), blk, 0, stream>>>(xn, WqkvT, QKV, nullptr, nullptr,
                                                 4096, 3072, 1024);
    transpose_v<<<dim3(64, 2, 32), tb, 0, stream>>>(QKV, VtB);
    // paired, balanced: 512 blocks x 33 tile-iters
    attn_kernel<<<dim3(16, 16, 2), blk, 0, stream>>>(QKV, VtB, ctx);
    gemm_bt_ks<1><<<dim3(32, 8), dim3(1024), 0, stream>>>(ctx, WoT, h, bo, x,
                                                          4096, 1024, 1024);
    ln_kernel<<<4096, blk, 0, stream>>>(h, scale2, shift2, xn);
    gemm_bt<2><<<dim3(32, 32), blk, 0, stream>>>(xn, W1T, g, b1, nullptr, 4096, 4096, 1024);
    gemm_bt_ks<1><<<dim3(32, 8), dim3(1024), 0, stream>>>(g, W2T, out, b2, h,
                                                          4096, 1024, 4096);
}

// Round 6
// 305.556 us; speedup vs baseline: 1.2018x; 1.0274x over previous
//
#include <hip/hip_runtime.h>
#include <hip/hip_bf16.h>

typedef __attribute__((ext_vector_type(4))) float f32x4;
typedef __attribute__((ext_vector_type(8))) short bf16x8;

#define AS1 __attribute__((address_space(1)))
#define AS3 __attribute__((address_space(3)))

__device__ __forceinline__ void gload16(const void* g, void* l) {
    __builtin_amdgcn_global_load_lds((AS1 const void*)g, (AS3 void*)l, 16, 0, 0);
}

__device__ __forceinline__ unsigned short f2bf(float f) {
    union { float f; unsigned int u; } v; v.f = f;
    unsigned int u = v.u;
    unsigned int r = (u + 0x7FFFu + ((u >> 16) & 1u)) >> 16;
    return (unsigned short)r;
}

__device__ __forceinline__ float gelu_t(float x) {
    float u = 0.7978845608028654f * (x + 0.044715f * x * x * x);
    return 0.5f * x * (1.0f + tanhf(u));
}

// ---------------------------------------------------------------------------
// Generic bf16 GEMM: C(MxN) = A(MxK) @ Bt(NxK)^T  [+ epilogue]
// EPI 0: store bf16 | EPI 1: v+bias[col]+res -> f32 | EPI 2: gelu(v+bias)->bf16
// ---------------------------------------------------------------------------
template<int EPI>
__global__ __launch_bounds__(256) void gemm_bt(
    const unsigned short* __restrict__ A,
    const unsigned short* __restrict__ Bt,
    void* __restrict__ C,
    const float* __restrict__ bias,
    const float* __restrict__ res,
    int M, int N, int K)
{
    __shared__ alignas(16) unsigned short As[128 * 32];
    __shared__ alignas(16) unsigned short Bs[128 * 32];
    const int t = threadIdx.x;
    const int lane = t & 63;
    const int w = t >> 6;
    const int la = lane & 15, lg = lane >> 4;
    const int brow = blockIdx.x * 128, bcol = blockIdx.y * 128;
    const int wr = (w >> 1) * 64, wc = (w & 1) * 64;

    const int srow = t >> 2;
    const int scol = (t & 3) * 8;
    const unsigned short* aS0 = A + (size_t)(brow + srow) * K + scol;
    const unsigned short* aS1 = A + (size_t)(brow + 64 + srow) * K + scol;
    const unsigned short* bS0 = Bt + (size_t)(bcol + srow) * K + scol;
    const unsigned short* bS1 = Bt + (size_t)(bcol + 64 + srow) * K + scol;
    unsigned short* aD = As + t * 8;
    unsigned short* bD = Bs + t * 8;

    f32x4 acc[4][4];
#pragma unroll
    for (int m = 0; m < 4; m++)
#pragma unroll
        for (int n = 0; n < 4; n++)
            acc[m][n] = (f32x4){0.f, 0.f, 0.f, 0.f};

    for (int k0 = 0; k0 < K; k0 += 32) {
        __syncthreads();
        gload16(aS0 + k0, aD);
        gload16(aS1 + k0, aD + 2048);
        gload16(bS0 + k0, bD);
        gload16(bS1 + k0, bD + 2048);
        __syncthreads();

        bf16x8 af[4], bfv[4];
#pragma unroll
        for (int m = 0; m < 4; m++)
            af[m] = *(const bf16x8*)(As + (wr + m * 16 + la) * 32 + lg * 8);
#pragma unroll
        for (int n = 0; n < 4; n++)
            bfv[n] = *(const bf16x8*)(Bs + (wc + n * 16 + la) * 32 + lg * 8);
#pragma unroll
        for (int m = 0; m < 4; m++)
#pragma unroll
            for (int n = 0; n < 4; n++)
                acc[m][n] = __builtin_amdgcn_mfma_f32_16x16x32_bf16(
                    af[m], bfv[n], acc[m][n], 0, 0, 0);
    }

#pragma unroll
    for (int m = 0; m < 4; m++)
#pragma unroll
        for (int n = 0; n < 4; n++)
#pragma unroll
            for (int j = 0; j < 4; j++) {
                int row = brow + wr + m * 16 + lg * 4 + j;
                int col = bcol + wc + n * 16 + la;
                float v = acc[m][n][j];
                if (EPI == 0) {
                    ((unsigned short*)C)[(size_t)row * N + col] = f2bf(v);
                } else if (EPI == 1) {
                    ((float*)C)[(size_t)row * N + col] =
                        v + bias[col] + res[(size_t)row * N + col];
                } else {
                    ((unsigned short*)C)[(size_t)row * N + col] =
                        f2bf(gelu_t(v + bias[col]));
                }
            }
}

// ---------------------------------------------------------------------------
// Split-K grouped GEMM for small grids (N=1024 -> only 256 blocks at 128x128).
// ---------------------------------------------------------------------------
template<int EPI>
__global__ __launch_bounds__(1024) void gemm_bt_ks(
    const unsigned short* __restrict__ A,
    const unsigned short* __restrict__ Bt,
    void* __restrict__ C,
    const float* __restrict__ bias,
    const float* __restrict__ res,
    int M, int N, int K)
{
    __shared__ alignas(16) char smem[128 * 132 * 4];
    const int t = threadIdx.x;
    const int g = t >> 8;
    const int tl = t & 255;
    const int lane = t & 63;
    const int w = tl >> 6;
    const int la = lane & 15, lg = lane >> 4;
    const int brow = blockIdx.x * 128, bcol = blockIdx.y * 128;
    const int wr = (w >> 1) * 64, wc = (w & 1) * 64;

    const int Kg = K >> 2;
    const int kbase = g * Kg;
    unsigned short* Asg = (unsigned short*)(smem + g * 16384);
    unsigned short* Bsg = Asg + 4096;

    const int srow = tl >> 2;
    const int scol = (tl & 3) * 8;
    const unsigned short* aS0 = A + (size_t)(brow + srow) * K + kbase + scol;
    const unsigned short* aS1 = A + (size_t)(brow + 64 + srow) * K + kbase + scol;
    const unsigned short* bS0 = Bt + (size_t)(bcol + srow) * K + kbase + scol;
    const unsigned short* bS1 = Bt + (size_t)(bcol + 64 + srow) * K + kbase + scol;
    unsigned short* aD = Asg + tl * 8;
    unsigned short* bD = Bsg + tl * 8;

    f32x4 acc[4][4];
#pragma unroll
    for (int m = 0; m < 4; m++)
#pragma unroll
        for (int n = 0; n < 4; n++)
            acc[m][n] = (f32x4){0.f, 0.f, 0.f, 0.f};

    for (int k0 = 0; k0 < Kg; k0 += 32) {
        __syncthreads();
        gload16(aS0 + k0, aD);
        gload16(aS1 + k0, aD + 2048);
        gload16(bS0 + k0, bD);
        gload16(bS1 + k0, bD + 2048);
        __syncthreads();

        bf16x8 af[4], bfv[4];
#pragma unroll
        for (int m = 0; m < 4; m++)
            af[m] = *(const bf16x8*)(Asg + (wr + m * 16 + la) * 32 + lg * 8);
#pragma unroll
        for (int n = 0; n < 4; n++)
            bfv[n] = *(const bf16x8*)(Bsg + (wc + n * 16 + la) * 32 + lg * 8);
#pragma unroll
        for (int m = 0; m < 4; m++)
#pragma unroll
            for (int n = 0; n < 4; n++)
                acc[m][n] = __builtin_amdgcn_mfma_f32_16x16x32_bf16(
                    af[m], bfv[n], acc[m][n], 0, 0, 0);
    }

    float* cbuf = (float*)smem;
    for (int s = 3; s >= 1; --s) {
        __syncthreads();
        if (g == s) {
#pragma unroll
            for (int m = 0; m < 4; m++)
#pragma unroll
                for (int n = 0; n < 4; n++)
#pragma unroll
                    for (int j = 0; j < 4; j++)
                        cbuf[(wr + m * 16 + lg * 4 + j) * 132 + wc + n * 16 + la] =
                            acc[m][n][j];
        }
        __syncthreads();
        if (g == 0) {
#pragma unroll
            for (int m = 0; m < 4; m++)
#pragma unroll
                for (int n = 0; n < 4; n++)
#pragma unroll
                    for (int j = 0; j < 4; j++)
                        acc[m][n][j] +=
                            cbuf[(wr + m * 16 + lg * 4 + j) * 132 + wc + n * 16 + la];
        }
    }
    if (g != 0) return;

#pragma unroll
    for (int m = 0; m < 4; m++)
#pragma unroll
        for (int n = 0; n < 4; n++)
#pragma unroll
            for (int j = 0; j < 4; j++) {
                int row = brow + wr + m * 16 + lg * 4 + j;
                int col = bcol + wc + n * 16 + la;
                float v = acc[m][n][j];
                if (EPI == 0) {
                    ((unsigned short*)C)[(size_t)row * N + col] = f2bf(v);
                } else if (EPI == 1) {
                    ((float*)C)[(size_t)row * N + col] =
                        v + bias[col] + res[(size_t)row * N + col];
                } else {
                    ((unsigned short*)C)[(size_t)row * N + col] =
                        f2bf(gelu_t(v + bias[col]));
                }
            }
}

// ---------------------------------------------------------------------------
// Causal flash attention: paired q-tiles (p, 31-p), 8 waves/block (512 thr).
// Waves 0-3 (group A) process EVEN kv tiles, waves 4-7 (group B) ODD tiles of
// the SAME q-tile; both groups share the staging barriers (uniform control
// flow), partials merged in LDS once per q-tile. 16 waves/CU.
// ---------------------------------------------------------------------------
__global__ __launch_bounds__(512, 4) void attn_kernel(
    const unsigned short* __restrict__ QKV,
    const unsigned short* __restrict__ Vt,
    unsigned short* __restrict__ ctx)
{
    // KVs[buf][group]: K tile (4096 sh) + V tile (4096 sh) = 16KB per slot
    __shared__ alignas(16) unsigned short KVs[2][2][8192];   // 64KB
    __shared__ alignas(16) unsigned short Ps[8][16 * 64];    // 16KB
    float* obuf = (float*)&KVs[0][0][0];    // merge: 64 rows x 68 f32 (17.4KB)
    float* mlbuf = (float*)&KVs[1][0][0];   // merge: m[64], l[64]

    const int t = threadIdx.x, lane = t & 63, w = t >> 6;
    const int wg = w >> 2;          // 0 = even tiles, 1 = odd tiles
    const int wl = w & 3;           // wave-in-group: q-row chunk
    const int la = lane & 15, lg = lane >> 4;
    const int p = blockIdx.x, h = blockIdx.y, b = blockIdx.z;
    const float C2 = 0.18033688011112042f;  // 0.125 * log2(e)

    const unsigned short* kg = QKV + (size_t)(b * 2048) * 3072 + 1024 + h * 64;
    const unsigned short* vg = Vt + (size_t)((b * 16 + h) * 64) * 2048;
    const int th = t & 255;
    const int sg = t >> 8;          // staging group: which tile of the pair
    const int srow = th >> 3;
    const int sxcol = (((th & 7) ^ (srow & 7)) * 8);

    unsigned short* pw = (unsigned short*)Ps[w];
    const int xk = la & 7;

    for (int half = 0; half < 2; ++half) {
        const int qt = half ? (31 - p) : p;
        const int qbase = qt * 64;

        const unsigned short* qp =
            QKV + (size_t)(b * 2048 + qbase + wl * 16 + la) * 3072 + h * 64;
        bf16x8 qf0 = *(const bf16x8*)(qp + lg * 8);
        bf16x8 qf1 = *(const bf16x8*)(qp + 32 + lg * 8);

        f32x4 o[4];
#pragma unroll
        for (int n = 0; n < 4; n++) o[n] = (f32x4){0.f, 0.f, 0.f, 0.f};
        float mrow[4] = {-1e30f, -1e30f, -1e30f, -1e30f};
        float lrow[4] = {0.f, 0.f, 0.f, 0.f};

        const int nt = qt + 1;
        const int npair = (nt + 1) >> 1;

        __syncthreads();   // previous half's LDS use (incl. merge) done
        {   // prologue: stage pair 0 (tiles 0 and 1) into buf 0
            const int kv0 = sg * 64;
            unsigned short* kd = KVs[0][sg];
            unsigned short* vd = kd + 4096;
            gload16(kg + (size_t)(kv0 + srow) * 3072 + sxcol, kd + th * 8);
            gload16(kg + (size_t)(kv0 + 32 + srow) * 3072 + sxcol, kd + 2048 + th * 8);
            gload16(vg + (size_t)srow * 2048 + kv0 + sxcol, vd + th * 8);
            gload16(vg + (size_t)(32 + srow) * 2048 + kv0 + sxcol, vd + 2048 + th * 8);
        }
        int cur = 0;
        for (int i = 0; i < npair; ++i) {
            __syncthreads();   // buf[cur] staged (barrier drains vmcnt)
            if (i + 1 < npair) {
                const int kv2 = (2 * (i + 1) + sg) * 64;
                unsigned short* kd = KVs[cur ^ 1][sg];
                unsigned short* vd = kd + 4096;
                gload16(kg + (size_t)(kv2 + srow) * 3072 + sxcol, kd + th * 8);
                gload16(kg + (size_t)(kv2 + 32 + srow) * 3072 + sxcol, kd + 2048 + th * 8);
                gload16(vg + (size_t)srow * 2048 + kv2 + sxcol, vd + th * 8);
                gload16(vg + (size_t)(32 + srow) * 2048 + kv2 + sxcol, vd + 2048 + th * 8);
            }
            const int tile = 2 * i + wg;
            if (tile < nt) {   // group-uniform guard; barriers stay outside
                const int kv = tile * 64;
                const unsigned short* Kc = KVs[cur][wg];
                const unsigned short* Vc = Kc + 4096;

                f32x4 sa[4];
                __builtin_amdgcn_s_setprio(1);
#pragma unroll
                for (int n = 0; n < 4; n++) {
                    f32x4 z = (f32x4){0.f, 0.f, 0.f, 0.f};
                    const unsigned short* kr = Kc + (n * 16 + la) * 64;
                    bf16x8 k0 = *(const bf16x8*)(kr + (lg ^ xk) * 8);
                    bf16x8 k1 = *(const bf16x8*)(kr + ((4 | lg) ^ xk) * 8);
                    z = __builtin_amdgcn_mfma_f32_16x16x32_bf16(qf0, k0, z, 0, 0, 0);
                    z = __builtin_amdgcn_mfma_f32_16x16x32_bf16(qf1, k1, z, 0, 0, 0);
                    sa[n] = z;
                }
                __builtin_amdgcn_s_setprio(0);
                if (tile == qt) {
#pragma unroll
                    for (int n = 0; n < 4; n++)
#pragma unroll
                        for (int j = 0; j < 4; j++) {
                            int qr = qbase + wl * 16 + lg * 4 + j;
                            int kc = kv + n * 16 + la;
                            if (kc > qr) sa[n][j] = -1e30f;
                        }
                }
                float pm[4];
#pragma unroll
                for (int j = 0; j < 4; j++)
                    pm[j] = fmaxf(fmaxf(sa[0][j], sa[1][j]), fmaxf(sa[2][j], sa[3][j]));
#pragma unroll
                for (int off = 1; off < 16; off <<= 1)
#pragma unroll
                    for (int j = 0; j < 4; j++)
                        pm[j] = fmaxf(pm[j], __shfl_xor(pm[j], off, 64));
                float alpha[4];
#pragma unroll
                for (int j = 0; j < 4; j++) {
                    float mn = fmaxf(mrow[j], pm[j]);
                    alpha[j] = exp2f((mrow[j] - mn) * C2);
                    mrow[j] = mn;
                }
                float psum[4] = {0.f, 0.f, 0.f, 0.f};
#pragma unroll
                for (int n = 0; n < 4; n++)
#pragma unroll
                    for (int j = 0; j < 4; j++) {
                        float pr = exp2f((sa[n][j] - mrow[j]) * C2);
                        sa[n][j] = pr;
                        psum[j] += pr;
                    }
#pragma unroll
                for (int off = 1; off < 16; off <<= 1)
#pragma unroll
                    for (int j = 0; j < 4; j++)
                        psum[j] += __shfl_xor(psum[j], off, 64);
#pragma unroll
                for (int j = 0; j < 4; j++) {
                    lrow[j] = lrow[j] * alpha[j] + psum[j];
                    o[0][j] *= alpha[j]; o[1][j] *= alpha[j];
                    o[2][j] *= alpha[j]; o[3][j] *= alpha[j];
                }
#pragma unroll
                for (int n = 0; n < 4; n++)
#pragma unroll
                    for (int j = 0; j < 4; j++) {
                        int qr = lg * 4 + j;
                        int col = n * 16 + la;
                        pw[qr * 64 + (((col >> 3) ^ (qr & 7)) * 8) + (col & 7)] =
                            f2bf(sa[n][j]);
                    }
                asm volatile("s_waitcnt lgkmcnt(0)" ::: "memory");
                __builtin_amdgcn_s_setprio(1);
#pragma unroll
                for (int kk = 0; kk < 2; kk++) {
                    bf16x8 pa = *(const bf16x8*)(pw + la * 64 + (((kk * 4 + lg) ^ xk) * 8));
#pragma unroll
                    for (int n = 0; n < 4; n++) {
                        bf16x8 vb = *(const bf16x8*)(
                            Vc + (n * 16 + la) * 64 + (((kk * 4 + lg) ^ xk) * 8));
                        o[n] = __builtin_amdgcn_mfma_f32_16x16x32_bf16(pa, vb, o[n], 0, 0, 0);
                    }
                }
                __builtin_amdgcn_s_setprio(0);
            }
            cur ^= 1;
        }

        // ---- merge group B into group A (staging LDS is idle now) ----
        __syncthreads();   // all compute done; no prefetch pending
        if (wg == 1) {
#pragma unroll
            for (int n = 0; n < 4; n++)
#pragma unroll
                for (int j = 0; j < 4; j++)
                    obuf[(wl * 16 + lg * 4 + j) * 68 + n * 16 + la] = o[n][j];
            if (la == 0) {
#pragma unroll
                for (int j = 0; j < 4; j++) {
                    mlbuf[wl * 16 + lg * 4 + j] = mrow[j];
                    mlbuf[64 + wl * 16 + lg * 4 + j] = lrow[j];
                }
            }
        }
        __syncthreads();
        if (wg == 0) {
            float ca[4], cb[4], inv[4], mb[4], lb[4];
#pragma unroll
            for (int j = 0; j < 4; j++) {
                mb[j] = mlbuf[wl * 16 + lg * 4 + j];
                lb[j] = mlbuf[64 + wl * 16 + lg * 4 + j];
                float m = fmaxf(mrow[j], mb[j]);
                ca[j] = exp2f((mrow[j] - m) * C2);
                cb[j] = exp2f((mb[j] - m) * C2);
                inv[j] = 1.0f / (lrow[j] * ca[j] + lb[j] * cb[j]);
            }
#pragma unroll
            for (int n = 0; n < 4; n++)
#pragma unroll
                for (int j = 0; j < 4; j++) {
                    float ov = o[n][j] * ca[j] +
                               obuf[(wl * 16 + lg * 4 + j) * 68 + n * 16 + la] * cb[j];
                    int row = b * 2048 + qbase + wl * 16 + lg * 4 + j;
                    int col = h * 64 + n * 16 + la;
                    ctx[(size_t)row * 1024 + col] = f2bf(ov * inv[j]);
                }
        }
    }
}

// ---------------------------------------------------------------------------
__global__ __launch_bounds__(256) void ln_kernel(
    const float* __restrict__ x, const float* __restrict__ scale,
    const float* __restrict__ shift, unsigned short* __restrict__ out)
{
    const int row = blockIdx.x, t = threadIdx.x;
    const int lane = t & 63, w = t >> 6;
    const float4 v = ((const float4*)(x + (size_t)row * 1024))[t];
    float s = v.x + v.y + v.z + v.w;
#pragma unroll
    for (int off = 1; off < 64; off <<= 1) s += __shfl_xor(s, off, 64);
    __shared__ float red[8];
    if (lane == 0) red[w] = s;
    __syncthreads();
    float mean = (red[0] + red[1] + red[2] + red[3]) * (1.0f / 1024.0f);
    float d0 = v.x - mean, d1 = v.y - mean, d2 = v.z - mean, d3 = v.w - mean;
    float q = d0 * d0 + d1 * d1 + d2 * d2 + d3 * d3;
#pragma unroll
    for (int off = 1; off < 64; off <<= 1) q += __shfl_xor(q, off, 64);
    if (lane == 0) red[4 + w] = q;
    __syncthreads();
    float var = (red[4] + red[5] + red[6] + red[7]) * (1.0f / 1023.0f);
    float rinv = rsqrtf(var + 1e-6f);
    const int c = t * 4;
    out[(size_t)row * 1024 + c + 0] = f2bf(scale[c + 0] * (d0 * rinv) + shift[c + 0]);
    out[(size_t)row * 1024 + c + 1] = f2bf(scale[c + 1] * (d1 * rinv) + shift[c + 1]);
    out[(size_t)row * 1024 + c + 2] = f2bf(scale[c + 2] * (d2 * rinv) + shift[c + 2]);
    out[(size_t)row * 1024 + c + 3] = f2bf(scale[c + 3] * (d3 * rinv) + shift[c + 3]);
}

// ---------------------------------------------------------------------------
__global__ __launch_bounds__(256) void transpose_w(
    const float* __restrict__ W, unsigned short* __restrict__ Wt, int K, int N)
{
    __shared__ float tile[32][33];
    const int nb = blockIdx.x * 32, kb = blockIdx.y * 32;
    const int tx = threadIdx.x, ty = threadIdx.y;
#pragma unroll
    for (int j = 0; j < 4; j++)
        tile[ty + j * 8][tx] = W[(size_t)(kb + ty + j * 8) * N + nb + tx];
    __syncthreads();
#pragma unroll
    for (int j = 0; j < 4; j++)
        Wt[(size_t)(nb + ty + j * 8) * K + kb + tx] = f2bf(tile[tx][ty + j * 8]);
}

// ---------------------------------------------------------------------------
__global__ __launch_bounds__(256) void transpose_v(
    const unsigned short* __restrict__ QKV, unsigned short* __restrict__ Vt)
{
    __shared__ unsigned short tile[32][33];
    const int sb = blockIdx.x * 32, hb = blockIdx.y * 32;
    const int bh = blockIdx.z;
    const int b = bh >> 4, h = bh & 15;
    const int tx = threadIdx.x, ty = threadIdx.y;
    const unsigned short* src = QKV + (size_t)(b * 2048) * 3072 + 2048 + h * 64;
#pragma unroll
    for (int j = 0; j < 4; j++)
        tile[ty + j * 8][tx] = src[(size_t)(sb + ty + j * 8) * 3072 + hb + tx];
    __syncthreads();
    unsigned short* dst = Vt + (size_t)((b * 16 + h) * 64) * 2048;
#pragma unroll
    for (int j = 0; j < 4; j++)
        dst[(size_t)(hb + ty + j * 8) * 2048 + sb + tx] = tile[tx][ty + j * 8];
}

// ---------------------------------------------------------------------------
extern "C" void kernel_launch(void* const* d_in, const int* in_sizes, int n_in,
                              void* d_out, int out_size, void* d_ws, size_t ws_size,
                              hipStream_t stream)
{
    const float* x      = (const float*)d_in[0];
    const float* Wq     = (const float*)d_in[1];
    const float* Wk     = (const float*)d_in[2];
    const float* Wv     = (const float*)d_in[3];
    const float* Wo     = (const float*)d_in[4];
    const float* bo     = (const float*)d_in[5];
    const float* W1     = (const float*)d_in[6];
    const float* b1     = (const float*)d_in[7];
    const float* W2     = (const float*)d_in[8];
    const float* b2     = (const float*)d_in[9];
    const float* scale1 = (const float*)d_in[10];
    const float* shift1 = (const float*)d_in[11];
    const float* scale2 = (const float*)d_in[12];
    const float* shift2 = (const float*)d_in[13];
    float* out = (float*)d_out;

    char* ws = (char*)d_ws;
    unsigned short* xn    = (unsigned short*)(ws);                   // 8MB (also yn)
    unsigned short* QKV   = (unsigned short*)(ws + (8ull << 20));    // 24MB
    unsigned short* VtB   = (unsigned short*)(ws + (32ull << 20));   // 8MB
    unsigned short* ctx   = (unsigned short*)(ws + (40ull << 20));   // 8MB
    unsigned short* g     = (unsigned short*)(ws + (8ull << 20));    // 32MB (reuse QKV+Vt)
    unsigned short* WqkvT = (unsigned short*)(ws + (48ull << 20));   // 6MB
    unsigned short* WoT   = (unsigned short*)(ws + (54ull << 20));   // 2MB
    unsigned short* W1T   = (unsigned short*)(ws + (56ull << 20));   // 8MB
    unsigned short* W2T   = (unsigned short*)(ws + (64ull << 20));   // 8MB -> 72MB total
    float* h = out;  // h lives in d_out

    dim3 blk(256);
    dim3 tb(32, 8);

    transpose_w<<<dim3(32, 32), tb, 0, stream>>>(Wq, WqkvT, 1024, 1024);
    transpose_w<<<dim3(32, 32), tb, 0, stream>>>(Wk, WqkvT + 1024 * 1024, 1024, 1024);
    transpose_w<<<dim3(32, 32), tb, 0, stream>>>(Wv, WqkvT + 2 * 1024 * 1024, 1024, 1024);
    transpose_w<<<dim3(32, 32), tb, 0, stream>>>(Wo, WoT, 1024, 1024);
    transpose_w<<<dim3(128, 32), tb, 0, stream>>>(W1, W1T, 1024, 4096);
    transpose_w<<<dim3(32, 128), tb, 0, stream>>>(W2, W2T, 4096, 1024);

    ln_kernel<<<4096, blk, 0, stream>>>(x, scale1, shift1, xn);
    gemm_bt<0><<<dim3(32, 24), blk, 0, stream>>>(xn, WqkvT, QKV, nullptr, nullptr,
                                                 4096, 3072, 1024);
    transpose_v<<<dim3(64, 2, 32), tb, 0, stream>>>(QKV, VtB);
    // paired + in-block KV split: 512 blocks x 8 waves = 16 waves/CU
    attn_kernel<<<dim3(16, 16, 2), dim3(512), 0, stream>>>(QKV, VtB, ctx);
    gemm_bt_ks<1><<<dim3(32, 8), dim3(1024), 0, stream>>>(ctx, WoT, h, bo, x,
                                                          4096, 1024, 1024);
    ln_kernel<<<4096, blk, 0, stream>>>(h, scale2, shift2, xn);
    gemm_bt<2><<<dim3(32, 32), blk, 0, stream>>>(xn, W1T, g, b1, nullptr, 4096, 4096, 1024);
    gemm_bt_ks<1><<<dim3(32, 8), dim3(1024), 0, stream>>>(g, W2T, out, b2, h,
                                                          4096, 1024, 4096);
}

// Round 7
// 289.088 us; speedup vs baseline: 1.2703x; 1.0570x over previous
//
#include <hip/hip_runtime.h>
#include <hip/hip_bf16.h>

typedef __attribute__((ext_vector_type(4))) float f32x4;
typedef __attribute__((ext_vector_type(8))) short bf16x8;

#define AS1 __attribute__((address_space(1)))
#define AS3 __attribute__((address_space(3)))

__device__ __forceinline__ void gload16(const void* g, void* l) {
    __builtin_amdgcn_global_load_lds((AS1 const void*)g, (AS3 void*)l, 16, 0, 0);
}

__device__ __forceinline__ unsigned short f2bf(float f) {
    union { float f; unsigned int u; } v; v.f = f;
    unsigned int u = v.u;
    unsigned int r = (u + 0x7FFFu + ((u >> 16) & 1u)) >> 16;
    return (unsigned short)r;
}

__device__ __forceinline__ float gelu_t(float x) {
    float u = 0.7978845608028654f * (x + 0.044715f * x * x * x);
    return 0.5f * x * (1.0f + tanhf(u));
}

// ---------------------------------------------------------------------------
// Generic bf16 GEMM: C(MxN) = A(MxK) @ Bt(NxK)^T  [+ epilogue]
// EPI 0: store bf16 | EPI 1: v+bias[col]+res -> f32 | EPI 2: gelu(v+bias)->bf16
// ---------------------------------------------------------------------------
template<int EPI>
__global__ __launch_bounds__(256) void gemm_bt(
    const unsigned short* __restrict__ A,
    const unsigned short* __restrict__ Bt,
    void* __restrict__ C,
    const float* __restrict__ bias,
    const float* __restrict__ res,
    int M, int N, int K)
{
    __shared__ alignas(16) unsigned short As[128 * 32];
    __shared__ alignas(16) unsigned short Bs[128 * 32];
    const int t = threadIdx.x;
    const int lane = t & 63;
    const int w = t >> 6;
    const int la = lane & 15, lg = lane >> 4;
    const int brow = blockIdx.x * 128, bcol = blockIdx.y * 128;
    const int wr = (w >> 1) * 64, wc = (w & 1) * 64;

    const int srow = t >> 2;
    const int scol = (t & 3) * 8;
    const unsigned short* aS0 = A + (size_t)(brow + srow) * K + scol;
    const unsigned short* aS1 = A + (size_t)(brow + 64 + srow) * K + scol;
    const unsigned short* bS0 = Bt + (size_t)(bcol + srow) * K + scol;
    const unsigned short* bS1 = Bt + (size_t)(bcol + 64 + srow) * K + scol;
    unsigned short* aD = As + t * 8;
    unsigned short* bD = Bs + t * 8;

    f32x4 acc[4][4];
#pragma unroll
    for (int m = 0; m < 4; m++)
#pragma unroll
        for (int n = 0; n < 4; n++)
            acc[m][n] = (f32x4){0.f, 0.f, 0.f, 0.f};

    for (int k0 = 0; k0 < K; k0 += 32) {
        __syncthreads();
        gload16(aS0 + k0, aD);
        gload16(aS1 + k0, aD + 2048);
        gload16(bS0 + k0, bD);
        gload16(bS1 + k0, bD + 2048);
        __syncthreads();

        bf16x8 af[4], bfv[4];
#pragma unroll
        for (int m = 0; m < 4; m++)
            af[m] = *(const bf16x8*)(As + (wr + m * 16 + la) * 32 + lg * 8);
#pragma unroll
        for (int n = 0; n < 4; n++)
            bfv[n] = *(const bf16x8*)(Bs + (wc + n * 16 + la) * 32 + lg * 8);
#pragma unroll
        for (int m = 0; m < 4; m++)
#pragma unroll
            for (int n = 0; n < 4; n++)
                acc[m][n] = __builtin_amdgcn_mfma_f32_16x16x32_bf16(
                    af[m], bfv[n], acc[m][n], 0, 0, 0);
    }

#pragma unroll
    for (int m = 0; m < 4; m++)
#pragma unroll
        for (int n = 0; n < 4; n++)
#pragma unroll
            for (int j = 0; j < 4; j++) {
                int row = brow + wr + m * 16 + lg * 4 + j;
                int col = bcol + wc + n * 16 + la;
                float v = acc[m][n][j];
                if (EPI == 0) {
                    ((unsigned short*)C)[(size_t)row * N + col] = f2bf(v);
                } else if (EPI == 1) {
                    ((float*)C)[(size_t)row * N + col] =
                        v + bias[col] + res[(size_t)row * N + col];
                } else {
                    ((unsigned short*)C)[(size_t)row * N + col] =
                        f2bf(gelu_t(v + bias[col]));
                }
            }
}

// ---------------------------------------------------------------------------
// Split-K grouped GEMM for small grids (N=1024 -> only 256 blocks at 128x128).
// ---------------------------------------------------------------------------
template<int EPI>
__global__ __launch_bounds__(1024) void gemm_bt_ks(
    const unsigned short* __restrict__ A,
    const unsigned short* __restrict__ Bt,
    void* __restrict__ C,
    const float* __restrict__ bias,
    const float* __restrict__ res,
    int M, int N, int K)
{
    __shared__ alignas(16) char smem[128 * 132 * 4];
    const int t = threadIdx.x;
    const int g = t >> 8;
    const int tl = t & 255;
    const int lane = t & 63;
    const int w = tl >> 6;
    const int la = lane & 15, lg = lane >> 4;
    const int brow = blockIdx.x * 128, bcol = blockIdx.y * 128;
    const int wr = (w >> 1) * 64, wc = (w & 1) * 64;

    const int Kg = K >> 2;
    const int kbase = g * Kg;
    unsigned short* Asg = (unsigned short*)(smem + g * 16384);
    unsigned short* Bsg = Asg + 4096;

    const int srow = tl >> 2;
    const int scol = (tl & 3) * 8;
    const unsigned short* aS0 = A + (size_t)(brow + srow) * K + kbase + scol;
    const unsigned short* aS1 = A + (size_t)(brow + 64 + srow) * K + kbase + scol;
    const unsigned short* bS0 = Bt + (size_t)(bcol + srow) * K + kbase + scol;
    const unsigned short* bS1 = Bt + (size_t)(bcol + 64 + srow) * K + kbase + scol;
    unsigned short* aD = Asg + tl * 8;
    unsigned short* bD = Bsg + tl * 8;

    f32x4 acc[4][4];
#pragma unroll
    for (int m = 0; m < 4; m++)
#pragma unroll
        for (int n = 0; n < 4; n++)
            acc[m][n] = (f32x4){0.f, 0.f, 0.f, 0.f};

    for (int k0 = 0; k0 < Kg; k0 += 32) {
        __syncthreads();
        gload16(aS0 + k0, aD);
        gload16(aS1 + k0, aD + 2048);
        gload16(bS0 + k0, bD);
        gload16(bS1 + k0, bD + 2048);
        __syncthreads();

        bf16x8 af[4], bfv[4];
#pragma unroll
        for (int m = 0; m < 4; m++)
            af[m] = *(const bf16x8*)(Asg + (wr + m * 16 + la) * 32 + lg * 8);
#pragma unroll
        for (int n = 0; n < 4; n++)
            bfv[n] = *(const bf16x8*)(Bsg + (wc + n * 16 + la) * 32 + lg * 8);
#pragma unroll
        for (int m = 0; m < 4; m++)
#pragma unroll
            for (int n = 0; n < 4; n++)
                acc[m][n] = __builtin_amdgcn_mfma_f32_16x16x32_bf16(
                    af[m], bfv[n], acc[m][n], 0, 0, 0);
    }

    float* cbuf = (float*)smem;
    for (int s = 3; s >= 1; --s) {
        __syncthreads();
        if (g == s) {
#pragma unroll
            for (int m = 0; m < 4; m++)
#pragma unroll
                for (int n = 0; n < 4; n++)
#pragma unroll
                    for (int j = 0; j < 4; j++)
                        cbuf[(wr + m * 16 + lg * 4 + j) * 132 + wc + n * 16 + la] =
                            acc[m][n][j];
        }
        __syncthreads();
        if (g == 0) {
#pragma unroll
            for (int m = 0; m < 4; m++)
#pragma unroll
                for (int n = 0; n < 4; n++)
#pragma unroll
                    for (int j = 0; j < 4; j++)
                        acc[m][n][j] +=
                            cbuf[(wr + m * 16 + lg * 4 + j) * 132 + wc + n * 16 + la];
        }
    }
    if (g != 0) return;

#pragma unroll
    for (int m = 0; m < 4; m++)
#pragma unroll
        for (int n = 0; n < 4; n++)
#pragma unroll
            for (int j = 0; j < 4; j++) {
                int row = brow + wr + m * 16 + lg * 4 + j;
                int col = bcol + wc + n * 16 + la;
                float v = acc[m][n][j];
                if (EPI == 0) {
                    ((unsigned short*)C)[(size_t)row * N + col] = f2bf(v);
                } else if (EPI == 1) {
                    ((float*)C)[(size_t)row * N + col] =
                        v + bias[col] + res[(size_t)row * N + col];
                } else {
                    ((unsigned short*)C)[(size_t)row * N + col] =
                        f2bf(gelu_t(v + bias[col]));
                }
            }
}

// ---------------------------------------------------------------------------
// Causal flash attention: paired q-tiles (p, 31-p), 8 waves (group A = even
// kv tiles, group B = odd), double-buffered staging.
// SWAPPED QK^T (S^T = mfma(K, Q)): each lane owns ONE q-row (la) -> softmax
// reduce = 15 local fmax + 2 shfl_xor; per-lane scalar (m,l,alpha) state;
// P packed via v_cvt_pk_bf16_f32, written as 8x b32; alpha/inv broadcast to
// PV C-layout rows via 4 ds_bpermute.
// ---------------------------------------------------------------------------
__global__ __launch_bounds__(512, 4) void attn_kernel(
    const unsigned short* __restrict__ QKV,
    const unsigned short* __restrict__ Vt,
    unsigned short* __restrict__ ctx)
{
    __shared__ alignas(16) unsigned short KVs[2][2][8192];   // 64KB
    __shared__ alignas(16) unsigned short Ps[8][16 * 64];    // 16KB
    float* obuf = (float*)&KVs[0][0][0];    // merge: 64 rows x 68 f32
    float* mlbuf = (float*)&KVs[1][0][0];   // merge: m[64], l[64]

    const int t = threadIdx.x, lane = t & 63, w = t >> 6;
    const int wg = w >> 2;          // 0 = even tiles, 1 = odd tiles
    const int wl = w & 3;           // wave-in-group: q-row chunk
    const int la = lane & 15, lg = lane >> 4;
    const int p = blockIdx.x, h = blockIdx.y, b = blockIdx.z;
    const float C2 = 0.18033688011112042f;  // 0.125 * log2(e)

    const unsigned short* kg = QKV + (size_t)(b * 2048) * 3072 + 1024 + h * 64;
    const unsigned short* vg = Vt + (size_t)((b * 16 + h) * 64) * 2048;
    const int th = t & 255;
    const int sg = t >> 8;          // staging group: which tile of the pair
    const int srow = th >> 3;
    const int sxcol = (((th & 7) ^ (srow & 7)) * 8);

    unsigned short* pw = (unsigned short*)Ps[w];
    const int xk = la & 7;

    for (int half = 0; half < 2; ++half) {
        const int qt = half ? (31 - p) : p;
        const int qbase = qt * 64;
        const int qr = qbase + wl * 16 + la;   // this lane's q-row

        const unsigned short* qp =
            QKV + (size_t)(b * 2048 + qbase + wl * 16 + la) * 3072 + h * 64;
        bf16x8 qf0 = *(const bf16x8*)(qp + lg * 8);
        bf16x8 qf1 = *(const bf16x8*)(qp + 32 + lg * 8);

        f32x4 o[4];
#pragma unroll
        for (int n = 0; n < 4; n++) o[n] = (f32x4){0.f, 0.f, 0.f, 0.f};
        float mrow = -1e30f, lrow = 0.f;

        const int nt = qt + 1;
        const int npair = (nt + 1) >> 1;

        __syncthreads();   // previous half's LDS use (incl. merge) done
        {   // prologue: stage pair 0 (tiles 0 and 1) into buf 0
            const int kv0 = sg * 64;
            unsigned short* kd = KVs[0][sg];
            unsigned short* vd = kd + 4096;
            gload16(kg + (size_t)(kv0 + srow) * 3072 + sxcol, kd + th * 8);
            gload16(kg + (size_t)(kv0 + 32 + srow) * 3072 + sxcol, kd + 2048 + th * 8);
            gload16(vg + (size_t)srow * 2048 + kv0 + sxcol, vd + th * 8);
            gload16(vg + (size_t)(32 + srow) * 2048 + kv0 + sxcol, vd + 2048 + th * 8);
        }
        int cur = 0;
        for (int i = 0; i < npair; ++i) {
            __syncthreads();   // buf[cur] staged (barrier drains vmcnt)
            if (i + 1 < npair) {
                const int kv2 = (2 * (i + 1) + sg) * 64;
                unsigned short* kd = KVs[cur ^ 1][sg];
                unsigned short* vd = kd + 4096;
                gload16(kg + (size_t)(kv2 + srow) * 3072 + sxcol, kd + th * 8);
                gload16(kg + (size_t)(kv2 + 32 + srow) * 3072 + sxcol, kd + 2048 + th * 8);
                gload16(vg + (size_t)srow * 2048 + kv2 + sxcol, vd + th * 8);
                gload16(vg + (size_t)(32 + srow) * 2048 + kv2 + sxcol, vd + 2048 + th * 8);
            }
            const int tile = 2 * i + wg;
            if (tile < nt) {   // group-uniform guard; barriers stay outside
                const int kv = tile * 64;
                const unsigned short* Kc = KVs[cur][wg];
                const unsigned short* Vc = Kc + 4096;

                // S^T: sa[n][j] = S[key = kv+16n+lg*4+j][qrow = la]
                f32x4 sa[4];
                __builtin_amdgcn_s_setprio(1);
#pragma unroll
                for (int n = 0; n < 4; n++) {
                    f32x4 z = (f32x4){0.f, 0.f, 0.f, 0.f};
                    const unsigned short* kr = Kc + (n * 16 + la) * 64;
                    bf16x8 k0 = *(const bf16x8*)(kr + (lg ^ xk) * 8);
                    bf16x8 k1 = *(const bf16x8*)(kr + ((4 | lg) ^ xk) * 8);
                    z = __builtin_amdgcn_mfma_f32_16x16x32_bf16(k0, qf0, z, 0, 0, 0);
                    z = __builtin_amdgcn_mfma_f32_16x16x32_bf16(k1, qf1, z, 0, 0, 0);
                    sa[n] = z;
                }
                __builtin_amdgcn_s_setprio(0);
                if (tile == qt) {
#pragma unroll
                    for (int n = 0; n < 4; n++)
#pragma unroll
                        for (int j = 0; j < 4; j++) {
                            int kc = kv + n * 16 + lg * 4 + j;
                            if (kc > qr) sa[n][j] = -1e30f;
                        }
                }
                // row max over 64 keys: 16 local + xor16 + xor32
                float pm0 = fmaxf(fmaxf(sa[0][0], sa[0][1]), fmaxf(sa[0][2], sa[0][3]));
                float pm1 = fmaxf(fmaxf(sa[1][0], sa[1][1]), fmaxf(sa[1][2], sa[1][3]));
                float pm2 = fmaxf(fmaxf(sa[2][0], sa[2][1]), fmaxf(sa[2][2], sa[2][3]));
                float pm3 = fmaxf(fmaxf(sa[3][0], sa[3][1]), fmaxf(sa[3][2], sa[3][3]));
                float pm = fmaxf(fmaxf(pm0, pm1), fmaxf(pm2, pm3));
                pm = fmaxf(pm, __shfl_xor(pm, 16, 64));
                pm = fmaxf(pm, __shfl_xor(pm, 32, 64));
                float mn = fmaxf(mrow, pm);
                float alpha = exp2f((mrow - mn) * C2);
                mrow = mn;
                float psum = 0.f;
#pragma unroll
                for (int n = 0; n < 4; n++)
#pragma unroll
                    for (int j = 0; j < 4; j++) {
                        float pr = exp2f((sa[n][j] - mrow) * C2);
                        sa[n][j] = pr;
                        psum += pr;
                    }
                psum += __shfl_xor(psum, 16, 64);
                psum += __shfl_xor(psum, 32, 64);
                lrow = lrow * alpha + psum;
                // pack P (bf16 pairs) -> LDS row la, swizzled chunks
#pragma unroll
                for (int n = 0; n < 4; n++)
#pragma unroll
                    for (int jp = 0; jp < 2; jp++) {
                        unsigned int pk;
                        asm("v_cvt_pk_bf16_f32 %0, %1, %2"
                            : "=v"(pk) : "v"(sa[n][2 * jp]), "v"(sa[n][2 * jp + 1]));
                        int col = 16 * n + lg * 4 + 2 * jp;
                        int idx = la * 64 + (((col >> 3) ^ xk) * 8) + (col & 7);
                        *(unsigned int*)(pw + idx) = pk;
                    }
                // broadcast alpha to PV C-layout rows (row = lg*4+j -> lane lg*4+j)
                float av[4];
#pragma unroll
                for (int j = 0; j < 4; j++)
                    av[j] = __shfl(alpha, lg * 4 + j, 64);
#pragma unroll
                for (int n = 0; n < 4; n++)
#pragma unroll
                    for (int j = 0; j < 4; j++)
                        o[n][j] *= av[j];
                asm volatile("s_waitcnt lgkmcnt(0)" ::: "memory");
                __builtin_amdgcn_s_setprio(1);
#pragma unroll
                for (int kk = 0; kk < 2; kk++) {
                    bf16x8 pa = *(const bf16x8*)(pw + la * 64 + (((kk * 4 + lg) ^ xk) * 8));
#pragma unroll
                    for (int n = 0; n < 4; n++) {
                        bf16x8 vb = *(const bf16x8*)(
                            Vc + (n * 16 + la) * 64 + (((kk * 4 + lg) ^ xk) * 8));
                        o[n] = __builtin_amdgcn_mfma_f32_16x16x32_bf16(pa, vb, o[n], 0, 0, 0);
                    }
                }
                __builtin_amdgcn_s_setprio(0);
            }
            cur ^= 1;
        }

        // ---- merge group B into group A (staging LDS is idle now) ----
        __syncthreads();   // all compute done; no prefetch pending
        if (wg == 1) {
#pragma unroll
            for (int n = 0; n < 4; n++)
#pragma unroll
                for (int j = 0; j < 4; j++)
                    obuf[(wl * 16 + lg * 4 + j) * 68 + n * 16 + la] = o[n][j];
            if (lg == 0) {                   // lanes 0..15: one per q-row
                mlbuf[wl * 16 + la] = mrow;
                mlbuf[64 + wl * 16 + la] = lrow;
            }
        }
        __syncthreads();
        if (wg == 0) {
            float mb = mlbuf[wl * 16 + la];
            float lb = mlbuf[64 + wl * 16 + la];
            float m = fmaxf(mrow, mb);
            float ca = exp2f((mrow - m) * C2);
            float cb = exp2f((mb - m) * C2);
            float linv = 1.0f / (lrow * ca + lb * cb);
            float cav[4], cbv[4], invv[4];
#pragma unroll
            for (int j = 0; j < 4; j++) {
                cav[j] = __shfl(ca, lg * 4 + j, 64);
                cbv[j] = __shfl(cb, lg * 4 + j, 64);
                invv[j] = __shfl(linv, lg * 4 + j, 64);
            }
#pragma unroll
            for (int n = 0; n < 4; n++)
#pragma unroll
                for (int j = 0; j < 4; j++) {
                    float ov = o[n][j] * cav[j] +
                               obuf[(wl * 16 + lg * 4 + j) * 68 + n * 16 + la] * cbv[j];
                    int row = b * 2048 + qbase + wl * 16 + lg * 4 + j;
                    int col = h * 64 + n * 16 + la;
                    ctx[(size_t)row * 1024 + col] = f2bf(ov * invv[j]);
                }
        }
    }
}

// ---------------------------------------------------------------------------
__global__ __launch_bounds__(256) void ln_kernel(
    const float* __restrict__ x, const float* __restrict__ scale,
    const float* __restrict__ shift, unsigned short* __restrict__ out)
{
    const int row = blockIdx.x, t = threadIdx.x;
    const int lane = t & 63, w = t >> 6;
    const float4 v = ((const float4*)(x + (size_t)row * 1024))[t];
    float s = v.x + v.y + v.z + v.w;
#pragma unroll
    for (int off = 1; off < 64; off <<= 1) s += __shfl_xor(s, off, 64);
    __shared__ float red[8];
    if (lane == 0) red[w] = s;
    __syncthreads();
    float mean = (red[0] + red[1] + red[2] + red[3]) * (1.0f / 1024.0f);
    float d0 = v.x - mean, d1 = v.y - mean, d2 = v.z - mean, d3 = v.w - mean;
    float q = d0 * d0 + d1 * d1 + d2 * d2 + d3 * d3;
#pragma unroll
    for (int off = 1; off < 64; off <<= 1) q += __shfl_xor(q, off, 64);
    if (lane == 0) red[4 + w] = q;
    __syncthreads();
    float var = (red[4] + red[5] + red[6] + red[7]) * (1.0f / 1023.0f);
    float rinv = rsqrtf(var + 1e-6f);
    const int c = t * 4;
    out[(size_t)row * 1024 + c + 0] = f2bf(scale[c + 0] * (d0 * rinv) + shift[c + 0]);
    out[(size_t)row * 1024 + c + 1] = f2bf(scale[c + 1] * (d1 * rinv) + shift[c + 1]);
    out[(size_t)row * 1024 + c + 2] = f2bf(scale[c + 2] * (d2 * rinv) + shift[c + 2]);
    out[(size_t)row * 1024 + c + 3] = f2bf(scale[c + 3] * (d3 * rinv) + shift[c + 3]);
}

// ---------------------------------------------------------------------------
__global__ __launch_bounds__(256) void transpose_w(
    const float* __restrict__ W, unsigned short* __restrict__ Wt, int K, int N)
{
    __shared__ float tile[32][33];
    const int nb = blockIdx.x * 32, kb = blockIdx.y * 32;
    const int tx = threadIdx.x, ty = threadIdx.y;
#pragma unroll
    for (int j = 0; j < 4; j++)
        tile[ty + j * 8][tx] = W[(size_t)(kb + ty + j * 8) * N + nb + tx];
    __syncthreads();
#pragma unroll
    for (int j = 0; j < 4; j++)
        Wt[(size_t)(nb + ty + j * 8) * K + kb + tx] = f2bf(tile[tx][ty + j * 8]);
}

// ---------------------------------------------------------------------------
__global__ __launch_bounds__(256) void transpose_v(
    const unsigned short* __restrict__ QKV, unsigned short* __restrict__ Vt)
{
    __shared__ unsigned short tile[32][33];
    const int sb = blockIdx.x * 32, hb = blockIdx.y * 32;
    const int bh = blockIdx.z;
    const int b = bh >> 4, h = bh & 15;
    const int tx = threadIdx.x, ty = threadIdx.y;
    const unsigned short* src = QKV + (size_t)(b * 2048) * 3072 + 2048 + h * 64;
#pragma unroll
    for (int j = 0; j < 4; j++)
        tile[ty + j * 8][tx] = src[(size_t)(sb + ty + j * 8) * 3072 + hb + tx];
    __syncthreads();
    unsigned short* dst = Vt + (size_t)((b * 16 + h) * 64) * 2048;
#pragma unroll
    for (int j = 0; j < 4; j++)
        dst[(size_t)(hb + ty + j * 8) * 2048 + sb + tx] = tile[tx][ty + j * 8];
}

// ---------------------------------------------------------------------------
extern "C" void kernel_launch(void* const* d_in, const int* in_sizes, int n_in,
                              void* d_out, int out_size, void* d_ws, size_t ws_size,
                              hipStream_t stream)
{
    const float* x      = (const float*)d_in[0];
    const float* Wq     = (const float*)d_in[1];
    const float* Wk     = (const float*)d_in[2];
    const float* Wv     = (const float*)d_in[3];
    const float* Wo     = (const float*)d_in[4];
    const float* bo     = (const float*)d_in[5];
    const float* W1     = (const float*)d_in[6];
    const float* b1     = (const float*)d_in[7];
    const float* W2     = (const float*)d_in[8];
    const float* b2     = (const float*)d_in[9];
    const float* scale1 = (const float*)d_in[10];
    const float* shift1 = (const float*)d_in[11];
    const float* scale2 = (const float*)d_in[12];
    const float* shift2 = (const float*)d_in[13];
    float* out = (float*)d_out;

    char* ws = (char*)d_ws;
    unsigned short* xn    = (unsigned short*)(ws);                   // 8MB (also yn)
    unsigned short* QKV   = (unsigned short*)(ws + (8ull << 20));    // 24MB
    unsigned short* VtB   = (unsigned short*)(ws + (32ull << 20));   // 8MB
    unsigned short* ctx   = (unsigned short*)(ws + (40ull << 20));   // 8MB
    unsigned short* g     = (unsigned short*)(ws + (8ull << 20));    // 32MB (reuse QKV+Vt)
    unsigned short* WqkvT = (unsigned short*)(ws + (48ull << 20));   // 6MB
    unsigned short* WoT   = (unsigned short*)(ws + (54ull << 20));   // 2MB
    unsigned short* W1T   = (unsigned short*)(ws + (56ull << 20));   // 8MB
    unsigned short* W2T   = (unsigned short*)(ws + (64ull << 20));   // 8MB -> 72MB total
    float* h = out;  // h lives in d_out

    dim3 blk(256);
    dim3 tb(32, 8);

    transpose_w<<<dim3(32, 32), tb, 0, stream>>>(Wq, WqkvT, 1024, 1024);
    transpose_w<<<dim3(32, 32), tb, 0, stream>>>(Wk, WqkvT + 1024 * 1024, 1024, 1024);
    transpose_w<<<dim3(32, 32), tb, 0, stream>>>(Wv, WqkvT + 2 * 1024 * 1024, 1024, 1024);
    transpose_w<<<dim3(32, 32), tb, 0, stream>>>(Wo, WoT, 1024, 1024);
    transpose_w<<<dim3(128, 32), tb, 0, stream>>>(W1, W1T, 1024, 4096);
    transpose_w<<<dim3(32, 128), tb, 0, stream>>>(W2, W2T, 4096, 1024);

    ln_kernel<<<4096, blk, 0, stream>>>(x, scale1, shift1, xn);
    gemm_bt<0><<<dim3(32, 24), blk, 0, stream>>>(xn, WqkvT, QKV, nullptr, nullptr,
                                                 4096, 3072, 1024);
    transpose_v<<<dim3(64, 2, 32), tb, 0, stream>>>(QKV, VtB);
    attn_kernel<<<dim3(16, 16, 2), dim3(512), 0, stream>>>(QKV, VtB, ctx);
    gemm_bt_ks<1><<<dim3(32, 8), dim3(1024), 0, stream>>>(ctx, WoT, h, bo, x,
                                                          4096, 1024, 1024);
    ln_kernel<<<4096, blk, 0, stream>>>(h, scale2, shift2, xn);
    gemm_bt<2><<<dim3(32, 32), blk, 0, stream>>>(xn, W1T, g, b1, nullptr, 4096, 4096, 1024);
    gemm_bt_ks<1><<<dim3(32, 8), dim3(1024), 0, stream>>>(g, W2T, out, b2, h,
                                                          4096, 1024, 4096);
}

// Round 8
// 259.445 us; speedup vs baseline: 1.4154x; 1.1143x over previous
//
#include <hip/hip_runtime.h>
#include <hip/hip_bf16.h>

typedef __attribute__((ext_vector_type(4))) float f32x4;
typedef __attribute__((ext_vector_type(8))) short bf16x8;

#define AS1 __attribute__((address_space(1)))
#define AS3 __attribute__((address_space(3)))

__device__ __forceinline__ void gload16(const void* g, void* l) {
    __builtin_amdgcn_global_load_lds((AS1 const void*)g, (AS3 void*)l, 16, 0, 0);
}

__device__ __forceinline__ unsigned short f2bf(float f) {
    union { float f; unsigned int u; } v; v.f = f;
    unsigned int u = v.u;
    unsigned int r = (u + 0x7FFFu + ((u >> 16) & 1u)) >> 16;
    return (unsigned short)r;
}

// gelu_tanh via sigmoid identity: 0.5*(1+tanh(u)) == 1/(1+e^{-2u})
// = x / (1 + exp2(-2*log2(e)*0.7978845608*(x + 0.044715 x^3)))
__device__ __forceinline__ float gelu_t(float x) {
    float x3 = x * x * x;
    float e = -2.3022082299f * (x + 0.044715f * x3);
    return x / (1.0f + exp2f(e));
}

// ---------------------------------------------------------------------------
// Generic bf16 GEMM: C(MxN) = A(MxK) @ Bt(NxK)^T  [+ epilogue]
// EPI 0: store bf16 | EPI 1: v+bias[col]+res -> f32 | EPI 2: gelu(v+bias)->bf16
// 128x128 tile, BK=32, 4 waves. 2-phase: dbuf LDS, counted vmcnt(4) so next
// tile's global_load_lds stay in flight across the barrier (T3/T4 minimum).
// ---------------------------------------------------------------------------
template<int EPI>
__global__ __launch_bounds__(256) void gemm_bt(
    const unsigned short* __restrict__ A,
    const unsigned short* __restrict__ Bt,
    void* __restrict__ C,
    const float* __restrict__ bias,
    const float* __restrict__ res,
    int M, int N, int K)
{
    __shared__ alignas(16) unsigned short As[2][128 * 32];
    __shared__ alignas(16) unsigned short Bs[2][128 * 32];
    const int t = threadIdx.x;
    const int lane = t & 63;
    const int w = t >> 6;
    const int la = lane & 15, lg = lane >> 4;
    const int brow = blockIdx.x * 128, bcol = blockIdx.y * 128;
    const int wr = (w >> 1) * 64, wc = (w & 1) * 64;

    const int srow = t >> 2;
    const int scol = (t & 3) * 8;
    const unsigned short* aS0 = A + (size_t)(brow + srow) * K + scol;
    const unsigned short* aS1 = A + (size_t)(brow + 64 + srow) * K + scol;
    const unsigned short* bS0 = Bt + (size_t)(bcol + srow) * K + scol;
    const unsigned short* bS1 = Bt + (size_t)(bcol + 64 + srow) * K + scol;

    f32x4 acc[4][4];
#pragma unroll
    for (int m = 0; m < 4; m++)
#pragma unroll
        for (int n = 0; n < 4; n++)
            acc[m][n] = (f32x4){0.f, 0.f, 0.f, 0.f};

    const int nk = K >> 5;
    {   // prologue: stage tile 0 into buf 0
        unsigned short* aD = As[0] + t * 8;
        unsigned short* bD = Bs[0] + t * 8;
        gload16(aS0, aD);
        gload16(aS1, aD + 2048);
        gload16(bS0, bD);
        gload16(bS1, bD + 2048);
    }
    int cur = 0;
    for (int kt = 0; kt < nk; ++kt) {
        if (kt + 1 < nk) {
            const int k1 = (kt + 1) << 5;
            unsigned short* aD = As[cur ^ 1] + t * 8;
            unsigned short* bD = Bs[cur ^ 1] + t * 8;
            gload16(aS0 + k1, aD);
            gload16(aS1 + k1, aD + 2048);
            gload16(bS0 + k1, bD);
            gload16(bS1 + k1, bD + 2048);
            asm volatile("s_waitcnt vmcnt(4)" ::: "memory");  // cur landed; next in flight
        } else {
            asm volatile("s_waitcnt vmcnt(0)" ::: "memory");
        }
        __builtin_amdgcn_s_barrier();
        __builtin_amdgcn_sched_barrier(0);

        const unsigned short* Ac = As[cur];
        const unsigned short* Bc = Bs[cur];
        bf16x8 af[4], bfv[4];
#pragma unroll
        for (int m = 0; m < 4; m++)
            af[m] = *(const bf16x8*)(Ac + (wr + m * 16 + la) * 32 + lg * 8);
#pragma unroll
        for (int n = 0; n < 4; n++)
            bfv[n] = *(const bf16x8*)(Bc + (wc + n * 16 + la) * 32 + lg * 8);
#pragma unroll
        for (int m = 0; m < 4; m++)
#pragma unroll
            for (int n = 0; n < 4; n++)
                acc[m][n] = __builtin_amdgcn_mfma_f32_16x16x32_bf16(
                    af[m], bfv[n], acc[m][n], 0, 0, 0);
        __builtin_amdgcn_sched_barrier(0);
        __builtin_amdgcn_s_barrier();   // reads done before buf overwrite (t+2)
        cur ^= 1;
    }

#pragma unroll
    for (int m = 0; m < 4; m++)
#pragma unroll
        for (int n = 0; n < 4; n++)
#pragma unroll
            for (int j = 0; j < 4; j++) {
                int row = brow + wr + m * 16 + lg * 4 + j;
                int col = bcol + wc + n * 16 + la;
                float v = acc[m][n][j];
                if (EPI == 0) {
                    ((unsigned short*)C)[(size_t)row * N + col] = f2bf(v);
                } else if (EPI == 1) {
                    ((float*)C)[(size_t)row * N + col] =
                        v + bias[col] + res[(size_t)row * N + col];
                } else {
                    ((unsigned short*)C)[(size_t)row * N + col] =
                        f2bf(gelu_t(v + bias[col]));
                }
            }
}

// ---------------------------------------------------------------------------
// Split-K grouped GEMM for small grids (N=1024 -> only 256 blocks at 128x128).
// 1024 threads = 4 groups x 4 waves, per-group K-range + per-group 2-phase
// dbuf staging (same counted-vmcnt pattern). Combine via LDS.
// ---------------------------------------------------------------------------
template<int EPI>
__global__ __launch_bounds__(1024) void gemm_bt_ks(
    const unsigned short* __restrict__ A,
    const unsigned short* __restrict__ Bt,
    void* __restrict__ C,
    const float* __restrict__ bias,
    const float* __restrict__ res,
    int M, int N, int K)
{
    // staging: 4 groups x 2 bufs x 16KB = 128KB; combine reuses it (67.5KB)
    __shared__ alignas(16) char smem[131072];
    const int t = threadIdx.x;
    const int g = t >> 8;
    const int tl = t & 255;
    const int lane = t & 63;
    const int w = tl >> 6;
    const int la = lane & 15, lg = lane >> 4;
    const int brow = blockIdx.x * 128, bcol = blockIdx.y * 128;
    const int wr = (w >> 1) * 64, wc = (w & 1) * 64;

    const int Kg = K >> 2;
    const int kbase = g * Kg;

    const int srow = tl >> 2;
    const int scol = (tl & 3) * 8;
    const unsigned short* aS0 = A + (size_t)(brow + srow) * K + kbase + scol;
    const unsigned short* aS1 = A + (size_t)(brow + 64 + srow) * K + kbase + scol;
    const unsigned short* bS0 = Bt + (size_t)(bcol + srow) * K + kbase + scol;
    const unsigned short* bS1 = Bt + (size_t)(bcol + 64 + srow) * K + kbase + scol;

    f32x4 acc[4][4];
#pragma unroll
    for (int m = 0; m < 4; m++)
#pragma unroll
        for (int n = 0; n < 4; n++)
            acc[m][n] = (f32x4){0.f, 0.f, 0.f, 0.f};

    const int nk = Kg >> 5;
    {   // prologue
        unsigned short* aD = (unsigned short*)(smem + g * 32768) + tl * 8;
        gload16(aS0, aD);
        gload16(aS1, aD + 2048);
        gload16(bS0, aD + 4096);
        gload16(bS1, aD + 6144);
    }
    int cur = 0;
    for (int kt = 0; kt < nk; ++kt) {
        if (kt + 1 < nk) {
            const int k1 = (kt + 1) << 5;
            unsigned short* aD =
                (unsigned short*)(smem + g * 32768 + (cur ^ 1) * 16384) + tl * 8;
            gload16(aS0 + k1, aD);
            gload16(aS1 + k1, aD + 2048);
            gload16(bS0 + k1, aD + 4096);
            gload16(bS1 + k1, aD + 6144);
            asm volatile("s_waitcnt vmcnt(4)" ::: "memory");
        } else {
            asm volatile("s_waitcnt vmcnt(0)" ::: "memory");
        }
        __builtin_amdgcn_s_barrier();
        __builtin_amdgcn_sched_barrier(0);

        const unsigned short* Asg =
            (const unsigned short*)(smem + g * 32768 + cur * 16384);
        const unsigned short* Bsg = Asg + 4096;
        bf16x8 af[4], bfv[4];
#pragma unroll
        for (int m = 0; m < 4; m++)
            af[m] = *(const bf16x8*)(Asg + (wr + m * 16 + la) * 32 + lg * 8);
#pragma unroll
        for (int n = 0; n < 4; n++)
            bfv[n] = *(const bf16x8*)(Bsg + (wc + n * 16 + la) * 32 + lg * 8);
#pragma unroll
        for (int m = 0; m < 4; m++)
#pragma unroll
            for (int n = 0; n < 4; n++)
                acc[m][n] = __builtin_amdgcn_mfma_f32_16x16x32_bf16(
                    af[m], bfv[n], acc[m][n], 0, 0, 0);
        __builtin_amdgcn_sched_barrier(0);
        __builtin_amdgcn_s_barrier();
        cur ^= 1;
    }

    float* cbuf = (float*)smem;
    for (int s = 3; s >= 1; --s) {
        __syncthreads();
        if (g == s) {
#pragma unroll
            for (int m = 0; m < 4; m++)
#pragma unroll
                for (int n = 0; n < 4; n++)
#pragma unroll
                    for (int j = 0; j < 4; j++)
                        cbuf[(wr + m * 16 + lg * 4 + j) * 132 + wc + n * 16 + la] =
                            acc[m][n][j];
        }
        __syncthreads();
        if (g == 0) {
#pragma unroll
            for (int m = 0; m < 4; m++)
#pragma unroll
                for (int n = 0; n < 4; n++)
#pragma unroll
                    for (int j = 0; j < 4; j++)
                        acc[m][n][j] +=
                            cbuf[(wr + m * 16 + lg * 4 + j) * 132 + wc + n * 16 + la];
        }
    }
    if (g != 0) return;

#pragma unroll
    for (int m = 0; m < 4; m++)
#pragma unroll
        for (int n = 0; n < 4; n++)
#pragma unroll
            for (int j = 0; j < 4; j++) {
                int row = brow + wr + m * 16 + lg * 4 + j;
                int col = bcol + wc + n * 16 + la;
                float v = acc[m][n][j];
                if (EPI == 0) {
                    ((unsigned short*)C)[(size_t)row * N + col] = f2bf(v);
                } else if (EPI == 1) {
                    ((float*)C)[(size_t)row * N + col] =
                        v + bias[col] + res[(size_t)row * N + col];
                } else {
                    ((unsigned short*)C)[(size_t)row * N + col] =
                        f2bf(gelu_t(v + bias[col]));
                }
            }
}

// ---------------------------------------------------------------------------
// Causal flash attention: paired q-tiles (p, 31-p), 8 waves (group A = even
// kv tiles, group B = odd), double-buffered staging, swapped QK^T in-register
// softmax (lane owns one q-row).
// ---------------------------------------------------------------------------
__global__ __launch_bounds__(512, 4) void attn_kernel(
    const unsigned short* __restrict__ QKV,
    const unsigned short* __restrict__ Vt,
    unsigned short* __restrict__ ctx)
{
    __shared__ alignas(16) unsigned short KVs[2][2][8192];   // 64KB
    __shared__ alignas(16) unsigned short Ps[8][16 * 64];    // 16KB
    float* obuf = (float*)&KVs[0][0][0];    // merge: 64 rows x 68 f32
    float* mlbuf = (float*)&KVs[1][0][0];   // merge: m[64], l[64]

    const int t = threadIdx.x, lane = t & 63, w = t >> 6;
    const int wg = w >> 2;          // 0 = even tiles, 1 = odd tiles
    const int wl = w & 3;           // wave-in-group: q-row chunk
    const int la = lane & 15, lg = lane >> 4;
    const int p = blockIdx.x, h = blockIdx.y, b = blockIdx.z;
    const float C2 = 0.18033688011112042f;  // 0.125 * log2(e)

    const unsigned short* kg = QKV + (size_t)(b * 2048) * 3072 + 1024 + h * 64;
    const unsigned short* vg = Vt + (size_t)((b * 16 + h) * 64) * 2048;
    const int th = t & 255;
    const int sg = t >> 8;          // staging group: which tile of the pair
    const int srow = th >> 3;
    const int sxcol = (((th & 7) ^ (srow & 7)) * 8);

    unsigned short* pw = (unsigned short*)Ps[w];
    const int xk = la & 7;

    for (int half = 0; half < 2; ++half) {
        const int qt = half ? (31 - p) : p;
        const int qbase = qt * 64;
        const int qr = qbase + wl * 16 + la;   // this lane's q-row

        const unsigned short* qp =
            QKV + (size_t)(b * 2048 + qbase + wl * 16 + la) * 3072 + h * 64;
        bf16x8 qf0 = *(const bf16x8*)(qp + lg * 8);
        bf16x8 qf1 = *(const bf16x8*)(qp + 32 + lg * 8);

        f32x4 o[4];
#pragma unroll
        for (int n = 0; n < 4; n++) o[n] = (f32x4){0.f, 0.f, 0.f, 0.f};
        float mrow = -1e30f, lrow = 0.f;

        const int nt = qt + 1;
        const int npair = (nt + 1) >> 1;

        __syncthreads();   // previous half's LDS use (incl. merge) done
        {   // prologue: stage pair 0 (tiles 0 and 1) into buf 0
            const int kv0 = sg * 64;
            unsigned short* kd = KVs[0][sg];
            unsigned short* vd = kd + 4096;
            gload16(kg + (size_t)(kv0 + srow) * 3072 + sxcol, kd + th * 8);
            gload16(kg + (size_t)(kv0 + 32 + srow) * 3072 + sxcol, kd + 2048 + th * 8);
            gload16(vg + (size_t)srow * 2048 + kv0 + sxcol, vd + th * 8);
            gload16(vg + (size_t)(32 + srow) * 2048 + kv0 + sxcol, vd + 2048 + th * 8);
        }
        int cur = 0;
        for (int i = 0; i < npair; ++i) {
            __syncthreads();   // buf[cur] staged (barrier drains vmcnt)
            if (i + 1 < npair) {
                const int kv2 = (2 * (i + 1) + sg) * 64;
                unsigned short* kd = KVs[cur ^ 1][sg];
                unsigned short* vd = kd + 4096;
                gload16(kg + (size_t)(kv2 + srow) * 3072 + sxcol, kd + th * 8);
                gload16(kg + (size_t)(kv2 + 32 + srow) * 3072 + sxcol, kd + 2048 + th * 8);
                gload16(vg + (size_t)srow * 2048 + kv2 + sxcol, vd + th * 8);
                gload16(vg + (size_t)(32 + srow) * 2048 + kv2 + sxcol, vd + 2048 + th * 8);
            }
            const int tile = 2 * i + wg;
            if (tile < nt) {   // group-uniform guard; barriers stay outside
                const int kv = tile * 64;
                const unsigned short* Kc = KVs[cur][wg];
                const unsigned short* Vc = Kc + 4096;

                // S^T: sa[n][j] = S[key = kv+16n+lg*4+j][qrow = la]
                f32x4 sa[4];
                __builtin_amdgcn_s_setprio(1);
#pragma unroll
                for (int n = 0; n < 4; n++) {
                    f32x4 z = (f32x4){0.f, 0.f, 0.f, 0.f};
                    const unsigned short* kr = Kc + (n * 16 + la) * 64;
                    bf16x8 k0 = *(const bf16x8*)(kr + (lg ^ xk) * 8);
                    bf16x8 k1 = *(const bf16x8*)(kr + ((4 | lg) ^ xk) * 8);
                    z = __builtin_amdgcn_mfma_f32_16x16x32_bf16(k0, qf0, z, 0, 0, 0);
                    z = __builtin_amdgcn_mfma_f32_16x16x32_bf16(k1, qf1, z, 0, 0, 0);
                    sa[n] = z;
                }
                __builtin_amdgcn_s_setprio(0);
                if (tile == qt) {
#pragma unroll
                    for (int n = 0; n < 4; n++)
#pragma unroll
                        for (int j = 0; j < 4; j++) {
                            int kc = kv + n * 16 + lg * 4 + j;
                            if (kc > qr) sa[n][j] = -1e30f;
                        }
                }
                float pm0 = fmaxf(fmaxf(sa[0][0], sa[0][1]), fmaxf(sa[0][2], sa[0][3]));
                float pm1 = fmaxf(fmaxf(sa[1][0], sa[1][1]), fmaxf(sa[1][2], sa[1][3]));
                float pm2 = fmaxf(fmaxf(sa[2][0], sa[2][1]), fmaxf(sa[2][2], sa[2][3]));
                float pm3 = fmaxf(fmaxf(sa[3][0], sa[3][1]), fmaxf(sa[3][2], sa[3][3]));
                float pm = fmaxf(fmaxf(pm0, pm1), fmaxf(pm2, pm3));
                pm = fmaxf(pm, __shfl_xor(pm, 16, 64));
                pm = fmaxf(pm, __shfl_xor(pm, 32, 64));
                float mn = fmaxf(mrow, pm);
                float alpha = exp2f((mrow - mn) * C2);
                mrow = mn;
                float psum = 0.f;
#pragma unroll
                for (int n = 0; n < 4; n++)
#pragma unroll
                    for (int j = 0; j < 4; j++) {
                        float pr = exp2f((sa[n][j] - mrow) * C2);
                        sa[n][j] = pr;
                        psum += pr;
                    }
                psum += __shfl_xor(psum, 16, 64);
                psum += __shfl_xor(psum, 32, 64);
                lrow = lrow * alpha + psum;
#pragma unroll
                for (int n = 0; n < 4; n++)
#pragma unroll
                    for (int jp = 0; jp < 2; jp++) {
                        unsigned int pk;
                        asm("v_cvt_pk_bf16_f32 %0, %1, %2"
                            : "=v"(pk) : "v"(sa[n][2 * jp]), "v"(sa[n][2 * jp + 1]));
                        int col = 16 * n + lg * 4 + 2 * jp;
                        int idx = la * 64 + (((col >> 3) ^ xk) * 8) + (col & 7);
                        *(unsigned int*)(pw + idx) = pk;
                    }
                float av[4];
#pragma unroll
                for (int j = 0; j < 4; j++)
                    av[j] = __shfl(alpha, lg * 4 + j, 64);
#pragma unroll
                for (int n = 0; n < 4; n++)
#pragma unroll
                    for (int j = 0; j < 4; j++)
                        o[n][j] *= av[j];
                asm volatile("s_waitcnt lgkmcnt(0)" ::: "memory");
                __builtin_amdgcn_s_setprio(1);
#pragma unroll
                for (int kk = 0; kk < 2; kk++) {
                    bf16x8 pa = *(const bf16x8*)(pw + la * 64 + (((kk * 4 + lg) ^ xk) * 8));
#pragma unroll
                    for (int n = 0; n < 4; n++) {
                        bf16x8 vb = *(const bf16x8*)(
                            Vc + (n * 16 + la) * 64 + (((kk * 4 + lg) ^ xk) * 8));
                        o[n] = __builtin_amdgcn_mfma_f32_16x16x32_bf16(pa, vb, o[n], 0, 0, 0);
                    }
                }
                __builtin_amdgcn_s_setprio(0);
            }
            cur ^= 1;
        }

        // ---- merge group B into group A (staging LDS is idle now) ----
        __syncthreads();   // all compute done; no prefetch pending
        if (wg == 1) {
#pragma unroll
            for (int n = 0; n < 4; n++)
#pragma unroll
                for (int j = 0; j < 4; j++)
                    obuf[(wl * 16 + lg * 4 + j) * 68 + n * 16 + la] = o[n][j];
            if (lg == 0) {                   // lanes 0..15: one per q-row
                mlbuf[wl * 16 + la] = mrow;
                mlbuf[64 + wl * 16 + la] = lrow;
            }
        }
        __syncthreads();
        if (wg == 0) {
            float mb = mlbuf[wl * 16 + la];
            float lb = mlbuf[64 + wl * 16 + la];
            float m = fmaxf(mrow, mb);
            float ca = exp2f((mrow - m) * C2);
            float cb = exp2f((mb - m) * C2);
            float linv = 1.0f / (lrow * ca + lb * cb);
            float cav[4], cbv[4], invv[4];
#pragma unroll
            for (int j = 0; j < 4; j++) {
                cav[j] = __shfl(ca, lg * 4 + j, 64);
                cbv[j] = __shfl(cb, lg * 4 + j, 64);
                invv[j] = __shfl(linv, lg * 4 + j, 64);
            }
#pragma unroll
            for (int n = 0; n < 4; n++)
#pragma unroll
                for (int j = 0; j < 4; j++) {
                    float ov = o[n][j] * cav[j] +
                               obuf[(wl * 16 + lg * 4 + j) * 68 + n * 16 + la] * cbv[j];
                    int row = b * 2048 + qbase + wl * 16 + lg * 4 + j;
                    int col = h * 64 + n * 16 + la;
                    ctx[(size_t)row * 1024 + col] = f2bf(ov * invv[j]);
                }
        }
    }
}

// ---------------------------------------------------------------------------
__global__ __launch_bounds__(256) void ln_kernel(
    const float* __restrict__ x, const float* __restrict__ scale,
    const float* __restrict__ shift, unsigned short* __restrict__ out)
{
    const int row = blockIdx.x, t = threadIdx.x;
    const int lane = t & 63, w = t >> 6;
    const float4 v = ((const float4*)(x + (size_t)row * 1024))[t];
    float s = v.x + v.y + v.z + v.w;
#pragma unroll
    for (int off = 1; off < 64; off <<= 1) s += __shfl_xor(s, off, 64);
    __shared__ float red[8];
    if (lane == 0) red[w] = s;
    __syncthreads();
    float mean = (red[0] + red[1] + red[2] + red[3]) * (1.0f / 1024.0f);
    float d0 = v.x - mean, d1 = v.y - mean, d2 = v.z - mean, d3 = v.w - mean;
    float q = d0 * d0 + d1 * d1 + d2 * d2 + d3 * d3;
#pragma unroll
    for (int off = 1; off < 64; off <<= 1) q += __shfl_xor(q, off, 64);
    if (lane == 0) red[4 + w] = q;
    __syncthreads();
    float var = (red[4] + red[5] + red[6] + red[7]) * (1.0f / 1023.0f);
    float rinv = rsqrtf(var + 1e-6f);
    const int c = t * 4;
    out[(size_t)row * 1024 + c + 0] = f2bf(scale[c + 0] * (d0 * rinv) + shift[c + 0]);
    out[(size_t)row * 1024 + c + 1] = f2bf(scale[c + 1] * (d1 * rinv) + shift[c + 1]);
    out[(size_t)row * 1024 + c + 2] = f2bf(scale[c + 2] * (d2 * rinv) + shift[c + 2]);
    out[(size_t)row * 1024 + c + 3] = f2bf(scale[c + 3] * (d3 * rinv) + shift[c + 3]);
}

// ---------------------------------------------------------------------------
__global__ __launch_bounds__(256) void transpose_w(
    const float* __restrict__ W, unsigned short* __restrict__ Wt, int K, int N)
{
    __shared__ float tile[32][33];
    const int nb = blockIdx.x * 32, kb = blockIdx.y * 32;
    const int tx = threadIdx.x, ty = threadIdx.y;
#pragma unroll
    for (int j = 0; j < 4; j++)
        tile[ty + j * 8][tx] = W[(size_t)(kb + ty + j * 8) * N + nb + tx];
    __syncthreads();
#pragma unroll
    for (int j = 0; j < 4; j++)
        Wt[(size_t)(nb + ty + j * 8) * K + kb + tx] = f2bf(tile[tx][ty + j * 8]);
}

// ---------------------------------------------------------------------------
__global__ __launch_bounds__(256) void transpose_v(
    const unsigned short* __restrict__ QKV, unsigned short* __restrict__ Vt)
{
    __shared__ unsigned short tile[32][33];
    const int sb = blockIdx.x * 32, hb = blockIdx.y * 32;
    const int bh = blockIdx.z;
    const int b = bh >> 4, h = bh & 15;
    const int tx = threadIdx.x, ty = threadIdx.y;
    const unsigned short* src = QKV + (size_t)(b * 2048) * 3072 + 2048 + h * 64;
#pragma unroll
    for (int j = 0; j < 4; j++)
        tile[ty + j * 8][tx] = src[(size_t)(sb + ty + j * 8) * 3072 + hb + tx];
    __syncthreads();
    unsigned short* dst = Vt + (size_t)((b * 16 + h) * 64) * 2048;
#pragma unroll
    for (int j = 0; j < 4; j++)
        dst[(size_t)(hb + ty + j * 8) * 2048 + sb + tx] = tile[tx][ty + j * 8];
}

// ---------------------------------------------------------------------------
extern "C" void kernel_launch(void* const* d_in, const int* in_sizes, int n_in,
                              void* d_out, int out_size, void* d_ws, size_t ws_size,
                              hipStream_t stream)
{
    const float* x      = (const float*)d_in[0];
    const float* Wq     = (const float*)d_in[1];
    const float* Wk     = (const float*)d_in[2];
    const float* Wv     = (const float*)d_in[3];
    const float* Wo     = (const float*)d_in[4];
    const float* bo     = (const float*)d_in[5];
    const float* W1     = (const float*)d_in[6];
    const float* b1     = (const float*)d_in[7];
    const float* W2     = (const float*)d_in[8];
    const float* b2     = (const float*)d_in[9];
    const float* scale1 = (const float*)d_in[10];
    const float* shift1 = (const float*)d_in[11];
    const float* scale2 = (const float*)d_in[12];
    const float* shift2 = (const float*)d_in[13];
    float* out = (float*)d_out;

    char* ws = (char*)d_ws;
    unsigned short* xn    = (unsigned short*)(ws);                   // 8MB (also yn)
    unsigned short* QKV   = (unsigned short*)(ws + (8ull << 20));    // 24MB
    unsigned short* VtB   = (unsigned short*)(ws + (32ull << 20));   // 8MB
    unsigned short* ctx   = (unsigned short*)(ws + (40ull << 20));   // 8MB
    unsigned short* g     = (unsigned short*)(ws + (8ull << 20));    // 32MB (reuse QKV+Vt)
    unsigned short* WqkvT = (unsigned short*)(ws + (48ull << 20));   // 6MB
    unsigned short* WoT   = (unsigned short*)(ws + (54ull << 20));   // 2MB
    unsigned short* W1T   = (unsigned short*)(ws + (56ull << 20));   // 8MB
    unsigned short* W2T   = (unsigned short*)(ws + (64ull << 20));   // 8MB -> 72MB total
    float* h = out;  // h lives in d_out

    dim3 blk(256);
    dim3 tb(32, 8);

    transpose_w<<<dim3(32, 32), tb, 0, stream>>>(Wq, WqkvT, 1024, 1024);
    transpose_w<<<dim3(32, 32), tb, 0, stream>>>(Wk, WqkvT + 1024 * 1024, 1024, 1024);
    transpose_w<<<dim3(32, 32), tb, 0, stream>>>(Wv, WqkvT + 2 * 1024 * 1024, 1024, 1024);
    transpose_w<<<dim3(32, 32), tb, 0, stream>>>(Wo, WoT, 1024, 1024);
    transpose_w<<<dim3(128, 32), tb, 0, stream>>>(W1, W1T, 1024, 4096);
    transpose_w<<<dim3(32, 128), tb, 0, stream>>>(W2, W2T, 4096, 1024);

    ln_kernel<<<4096, blk, 0, stream>>>(x, scale1, shift1, xn);
    gemm_bt<0><<<dim3(32, 24), blk, 0, stream>>>(xn, WqkvT, QKV, nullptr, nullptr,
                                                 4096, 3072, 1024);
    transpose_v<<<dim3(64, 2, 32), tb, 0, stream>>>(QKV, VtB);
    attn_kernel<<<dim3(16, 16, 2), dim3(512), 0, stream>>>(QKV, VtB, ctx);
    gemm_bt_ks<1><<<dim3(32, 8), dim3(1024), 0, stream>>>(ctx, WoT, h, bo, x,
                                                          4096, 1024, 1024);
    ln_kernel<<<4096, blk, 0, stream>>>(h, scale2, shift2, xn);
    gemm_bt<2><<<dim3(32, 32), blk, 0, stream>>>(xn, W1T, g, b1, nullptr, 4096, 4096, 1024);
    gemm_bt_ks<1><<<dim3(32, 8), dim3(1024), 0, stream>>>(g, W2T, out, b2, h,
                                                          4096, 1024, 4096);
}